// Round 1
// 2748.498 us; speedup vs baseline: 1.1006x; 1.1006x over previous
//
#include <hip/hip_runtime.h>

typedef unsigned short u16;
typedef __attribute__((ext_vector_type(8))) short s8v;
typedef __attribute__((ext_vector_type(8))) __bf16 bfv8;
typedef __attribute__((ext_vector_type(4))) float f32x4;

#define L_DIM 1024
#define N_DIM 16384
#define R_DIM 128
#define PEN  -10000.0f

__device__ __forceinline__ float b2f(u16 x) { return __uint_as_float(((unsigned)x) << 16); }
__device__ __forceinline__ u16 f2bf(float f) {
    unsigned u = __float_as_uint(f);
    unsigned r = (u + 0x7FFFu + ((u >> 16) & 1u)) >> 16;
    return (u16)r;
}
__device__ __forceinline__ unsigned fmapu(float f) {
    unsigned u = __float_as_uint(f);
    return (u & 0x80000000u) ? ~u : (u | 0x80000000u);
}
__device__ __forceinline__ float funmap(unsigned u) {
    unsigned b = (u & 0x80000000u) ? (u & 0x7fffffffu) : ~u;
    return __uint_as_float(b);
}
// flag=0: 4-byte elements (int32 OR float32 bools); flag=1: 1-byte elements
__device__ __forceinline__ int mask_ok(const void* al, int fl, size_t idx) {
    if (fl) return ((const unsigned char*)al)[idx] != 0;
    return ((const unsigned*)al)[idx] != 0u;
}
// log of bf16-linear E entry, sentinel for exact zero
__device__ __forceinline__ float loge(u16 x) {
    float e = b2f(x);
    return (e > 0.f) ? __logf(e) : -1.0e30f;
}

__device__ __forceinline__ float blk_max(float x, float* scr) {
#pragma unroll
    for (int o = 32; o > 0; o >>= 1) x = fmaxf(x, __shfl_xor(x, o));
    __syncthreads();
    if ((threadIdx.x & 63) == 0) scr[threadIdx.x >> 6] = x;
    __syncthreads();
    return fmaxf(fmaxf(scr[0], scr[1]), fmaxf(scr[2], scr[3]));
}
__device__ __forceinline__ float blk_sum(float x, float* scr) {
#pragma unroll
    for (int o = 32; o > 0; o >>= 1) x += __shfl_xor(x, o);
    __syncthreads();
    if ((threadIdx.x & 63) == 0) scr[threadIdx.x >> 6] = x;
    __syncthreads();
    return scr[0] + scr[1] + scr[2] + scr[3];
}

// -------- detect allowed element width --------------------------------------
__global__ void detect_k(const unsigned* __restrict__ a, int* __restrict__ flag) {
    int bad = 0;
    for (int i = threadIdx.x; i < 4096; i += 256) {
        unsigned w = a[i];
        if (w != 0u && w != 1u && w != 0x3F800000u) bad = 1;
    }
    if (bad) *flag = 1;
}

// -------- bit-pack allowed: bits[cur*512 + (prev>>5)] bit (prev&31) ---------
// 256 MB (or 1 GB) coalesced read -> 32 MB write; 32 MB stays L3-resident.
__global__ __launch_bounds__(256) void pack_mask_k(const void* __restrict__ al,
                                                   const int* __restrict__ flag,
                                                   unsigned* __restrict__ bits) {
    const size_t wi = (size_t)blockIdx.x * 256 + threadIdx.x;  // output word idx
    const int fl = *flag;
    unsigned out = 0u;
    if (fl) {
        const uint4* p = (const uint4*)((const unsigned char*)al + wi * 32);
        uint4 a = p[0], b = p[1];
        unsigned v[8] = {a.x, a.y, a.z, a.w, b.x, b.y, b.z, b.w};
#pragma unroll
        for (int q = 0; q < 8; ++q)
#pragma unroll
            for (int e = 0; e < 4; ++e)
                if ((v[q] >> (e * 8)) & 0xFFu) out |= 1u << (q * 4 + e);
    } else {
        const uint4* p = (const uint4*)((const unsigned*)al + wi * 32);
#pragma unroll
        for (int q = 0; q < 8; ++q) {
            uint4 a = p[q];
            if (a.x) out |= 1u << (q * 4 + 0);
            if (a.y) out |= 1u << (q * 4 + 1);
            if (a.z) out |= 1u << (q * 4 + 2);
            if (a.w) out |= 1u << (q * 4 + 3);
        }
    }
    bits[wi] = out;
}

// -------- per-row top-128 (radix select) + log_softmax over the set ---------
__global__ __launch_bounds__(256) void topk_lsm_k(const float* __restrict__ U,
                                                  int* __restrict__ candg,
                                                  float* __restrict__ lsmg) {
    const int t = blockIdx.x;
    const float* row = U + (size_t)t * N_DIM;
    __shared__ unsigned hist[256];
    __shared__ int sel[2];
    __shared__ int cnts[2];
    __shared__ float vals[128];
    __shared__ int inds[128];
    __shared__ float scr[4];
    const int tid = threadIdx.x;
    unsigned prefix = 0;
    int kneed = 128;
    for (int pass = 0; pass < 4; ++pass) {
        const int sh = 24 - pass * 8;
        hist[tid] = 0;
        __syncthreads();
        for (int i = tid; i < N_DIM; i += 256) {
            unsigned u = __float_as_uint(row[i]);
            unsigned k = (u & 0x80000000u) ? ~u : (u | 0x80000000u);
            bool match = (pass == 0) || ((k >> (sh + 8)) == prefix);
            if (match) atomicAdd(&hist[(k >> sh) & 255u], 1u);
        }
        __syncthreads();
        if (tid == 0) {
            int acc = 0, d = 0;
            for (int dig = 255; dig >= 0; --dig) {
                int c = (int)hist[dig];
                if (acc + c >= kneed) { d = dig; break; }
                acc += c;
            }
            sel[0] = d; sel[1] = acc;
        }
        __syncthreads();
        kneed -= sel[1];
        prefix = (prefix << 8) | (unsigned)sel[0];
        __syncthreads();
    }
    const unsigned K = prefix;
    if (tid < 2) cnts[tid] = 0;
    if (tid < 128) { vals[tid] = -1.0e30f; inds[tid] = 0; }
    __syncthreads();
    for (int i = tid; i < N_DIM; i += 256) {
        float f = row[i];
        unsigned u = __float_as_uint(f);
        unsigned k = (u & 0x80000000u) ? ~u : (u | 0x80000000u);
        if (k > K) { int p = atomicAdd(&cnts[0], 1); if (p < 128) { vals[p] = f; inds[p] = i; } }
    }
    __syncthreads();
    const int cgt = min(cnts[0], 128);
    for (int i = tid; i < N_DIM; i += 256) {
        float f = row[i];
        unsigned u = __float_as_uint(f);
        unsigned k = (u & 0x80000000u) ? ~u : (u | 0x80000000u);
        if (k == K) {
            int p = atomicAdd(&cnts[1], 1);
            if (cgt + p < 128) { vals[cgt + p] = f; inds[cgt + p] = i; }
        }
    }
    __syncthreads();
    float xv = (tid < 128) ? vals[tid] : -3.0e38f;
    float mx = blk_max(xv, scr);
    float ex = (tid < 128) ? __expf(vals[tid] - mx) : 0.f;
    float sm = blk_sum(ex, scr);
    float lse = mx + __logf(fmaxf(sm, 1e-37f));
    if (tid < 128) {
        candg[t * 128 + tid] = min(max(inds[tid], 0), N_DIM - 1);
        lsmg[t * 128 + tid] = vals[tid] - lse;
    }
}

// -------- cast H to bf16 ----------------------------------------------------
__global__ void cast_h_k(const float* __restrict__ H, u16* __restrict__ Hbf) {
    size_t base = ((size_t)blockIdx.x * 256 + threadIdx.x) * 4;
    float4 f = *(const float4*)(H + base);
    ushort4 o;
    o.x = f2bf(f.x); o.y = f2bf(f.y); o.z = f2bf(f.z); o.w = f2bf(f.w);
    *(ushort4*)(Hbf + base) = o;
}

// -------- HW = H @ W (fp32 VALU, bf16 out); 8 rows per block ----------------
__global__ __launch_bounds__(256) void gemm_hw_k(const float* __restrict__ H,
                                                 const float* __restrict__ W,
                                                 u16* __restrict__ HWbf) {
    const int r0 = blockIdx.x * 8;
    __shared__ float Hl[8][512];
    for (int idx = threadIdx.x; idx < 8 * 512; idx += 256) {
        int r = idx >> 9, k = idx & 511;
        Hl[r][k] = H[(size_t)(r0 + r) * 512 + k];
    }
    __syncthreads();
    const int c = threadIdx.x;
    float acc0[8], acc1[8];
#pragma unroll
    for (int r = 0; r < 8; ++r) { acc0[r] = 0.f; acc1[r] = 0.f; }
    for (int k = 0; k < 512; ++k) {
        float w0 = W[(size_t)k * 512 + c];
        float w1 = W[(size_t)k * 512 + c + 256];
#pragma unroll
        for (int r = 0; r < 8; ++r) {
            float h = Hl[r][k];
            acc0[r] += h * w0;
            acc1[r] += h * w1;
        }
    }
#pragma unroll
    for (int r = 0; r < 8; ++r) {
        HWbf[(size_t)(r0 + r) * 512 + c] = f2bf(acc0[r]);
        HWbf[(size_t)(r0 + r) * 512 + c + 256] = f2bf(acc1[r]);
    }
}

// -------- per-step pair matrix via MFMA -> (E row-major bf16, c fp32) -------
// Per block t: C[i][j] = dot(HW[prev_i], H[cur_j]) (128x128, K=512) with
// mfma_f32_16x16x32_bf16; 4 waves in 2x2, 64x64 tile each, K-step 64,
// reg-staged LDS tiles with XOR swizzle (slot ^= row&7) -> conflict-free.
// Mask comes from the bit-packed 'bits' array, gathered into 2 KB of LDS
// while the first tile loads are in flight.
__global__ __launch_bounds__(256) void pair_k(const int* __restrict__ candg,
                                              const float* __restrict__ lsmg,
                                              const u16* __restrict__ HWbf,
                                              const u16* __restrict__ Hbf,
                                              const unsigned* __restrict__ bits,
                                              u16* __restrict__ Eg,
                                              float* __restrict__ cvec) {
    const int t = blockIdx.x + 1;
    __shared__ u16 tile[2][128 * 64];   // [0]=A (HW[prev]) [1]=B (H[cur]), swizzled
    __shared__ int sprev[128], scur[128];
    __shared__ unsigned maskw[128][4];  // maskw[j][i>>5] bit (i&31)
    __shared__ unsigned scm_u[128];
    __shared__ float cmf[128];
    const int tid = threadIdx.x;
    if (tid < 128) {
        sprev[tid] = min(max(candg[(t - 1) * 128 + tid], 0), N_DIM - 1);
        scur[tid]  = min(max(candg[t * 128 + tid], 0), N_DIM - 1);
        scm_u[tid] = 0u;
    }
    __syncthreads();

    const int lane = tid & 63, w = tid >> 6;
    const int wr = w >> 1, wc = w & 1;      // wave tile: rows wr*64.., cols wc*64..
    const int srow = lane >> 3, slot = lane & 7;
    const int lq = lane & 15, lh = lane >> 4;

    // staging: lane covers (row (w*4+q)*8+srow, 16B chunk 'slot'); swizzled LDS dest
    const u16* pA[4]; const u16* pB[4]; int wadr[4];
#pragma unroll
    for (int q = 0; q < 4; ++q) {
        int r = (w * 4 + q) * 8 + srow;
        pA[q] = HWbf + (size_t)sprev[r] * 512 + slot * 8;
        pB[q] = Hbf  + (size_t)scur[r] * 512 + slot * 8;
        wadr[q] = r * 64 + ((slot ^ srow) * 8);
    }
    s8v rA[4], rB[4];
#pragma unroll
    for (int q = 0; q < 4; ++q) { rA[q] = *(const s8v*)pA[q]; rB[q] = *(const s8v*)pB[q]; }

    // mask gather from bit-packed allowed (L3-resident); overlaps staging latency
    {
        const int j = tid & 127, ihalf = tid >> 7;
        const unsigned* rowp = bits + (size_t)scur[j] * 512;
        unsigned mw0 = 0u, mw1 = 0u;
#pragma unroll 8
        for (int kb = 0; kb < 32; ++kb) {
            int p0 = sprev[ihalf * 64 + kb];
            int p1 = sprev[ihalf * 64 + 32 + kb];
            mw0 |= ((rowp[p0 >> 5] >> (p0 & 31)) & 1u) << kb;
            mw1 |= ((rowp[p1 >> 5] >> (p1 & 31)) & 1u) << kb;
        }
        maskw[j][ihalf * 2]     = mw0;
        maskw[j][ihalf * 2 + 1] = mw1;
    }

    f32x4 acc[4][4];
#pragma unroll
    for (int a = 0; a < 4; ++a)
#pragma unroll
        for (int b = 0; b < 4; ++b) acc[a][b] = (f32x4){0.f, 0.f, 0.f, 0.f};

    for (int s = 0; s < 8; ++s) {
        __syncthreads();
#pragma unroll
        for (int q = 0; q < 4; ++q) {
            *(s8v*)&tile[0][wadr[q]] = rA[q];
            *(s8v*)&tile[1][wadr[q]] = rB[q];
        }
        __syncthreads();
        if (s < 7) {                       // prefetch next K-slice into regs
#pragma unroll
            for (int q = 0; q < 4; ++q) {
                pA[q] += 64; pB[q] += 64;
                rA[q] = *(const s8v*)pA[q];
                rB[q] = *(const s8v*)pB[q];
            }
        }
#pragma unroll
        for (int kk = 0; kk < 2; ++kk) {
            bfv8 aF[4], bF[4];
            const int sl = (((kk << 2) | lh) ^ (lq & 7)) * 8;   // swizzled 16B slot
#pragma unroll
            for (int b = 0; b < 4; ++b) {
                aF[b] = *(const bfv8*)&tile[0][(wr * 64 + b * 16 + lq) * 64 + sl];
                bF[b] = *(const bfv8*)&tile[1][(wc * 64 + b * 16 + lq) * 64 + sl];
            }
#pragma unroll
            for (int bi = 0; bi < 4; ++bi)
#pragma unroll
                for (int bj = 0; bj < 4; ++bj)
                    acc[bi][bj] = __builtin_amdgcn_mfma_f32_16x16x32_bf16(
                        aF[bi], bF[bj], acc[bi][bj], 0, 0, 0);
        }
    }

    // epilogue: mask, per-column (j) max over i, exp-normalize, store E
    // C/D layout: col j = wc*64+bj*16+(lane&15); row i = wr*64+bi*16+(lane>>4)*4+r
#pragma unroll
    for (int bj = 0; bj < 4; ++bj) {
        const int j = wc * 64 + bj * 16 + lq;
        float cm = -3.0e38f;
#pragma unroll
        for (int bi = 0; bi < 4; ++bi) {
#pragma unroll
            for (int r = 0; r < 4; ++r) {
                int i = wr * 64 + bi * 16 + lh * 4 + r;
                float v = acc[bi][bj][r];
                if (!((maskw[j][i >> 5] >> (i & 31)) & 1u)) v += PEN;
                acc[bi][bj][r] = v;
                cm = fmaxf(cm, v);
            }
        }
        cm = fmaxf(cm, __shfl_xor(cm, 16));   // merge i-quarters (same j)
        cm = fmaxf(cm, __shfl_xor(cm, 32));
        if (lane < 16) atomicMax(&scm_u[j], fmapu(cm));
    }
    __syncthreads();
    if (tid < 128) {
        float cm = funmap(scm_u[tid]);
        cmf[tid] = cm;
        cvec[(size_t)(t - 1) * 128 + tid] = cm + lsmg[(size_t)t * 128 + tid];
    }
    __syncthreads();
    // restage E through (now dead) tiles for coalesced stores
    u16* Ebuf = &tile[0][0];                // 16384 u16, contiguous
#pragma unroll
    for (int bj = 0; bj < 4; ++bj) {
        const int j = wc * 64 + bj * 16 + lq;
        const float cm = cmf[j];
#pragma unroll
        for (int bi = 0; bi < 4; ++bi) {
#pragma unroll
            for (int r = 0; r < 4; ++r) {
                int i = wr * 64 + bi * 16 + lh * 4 + r;
                float e = __expf(acc[bi][bj][r] - cm);   // arg <= 0 by construction
                e = fminf(fmaxf(e, 0.f), 1.0f);
                Ebuf[i * 128 + j] = f2bf(e);
            }
        }
    }
    __syncthreads();
    u16* Eo = Eg + (size_t)(t - 1) * 16384;
    for (int idx = tid; idx < 2048; idx += 256)
        ((s8v*)Eo)[idx] = ((const s8v*)Ebuf)[idx];
}

// -------- gold path scores --------------------------------------------------
__global__ __launch_bounds__(256) void score_k(const float* __restrict__ U,
                                               const int* __restrict__ gold,
                                               const void* __restrict__ allowed,
                                               const int* __restrict__ flag,
                                               const u16* __restrict__ HWbf,
                                               const u16* __restrict__ Hbf,
                                               float* __restrict__ accums) {
    const int t = blockIdx.x;
    __shared__ float scr[4];
    float part = 0.f;
    int gp = 0, gc = 0;
    if (t < L_DIM - 1) {
        gp = min(max(gold[t], 0), N_DIM - 1);
        gc = min(max(gold[t + 1], 0), N_DIM - 1);
        const u16* ar = HWbf + (size_t)gp * 512;
        const u16* br = Hbf + (size_t)gc * 512;
        for (int k = threadIdx.x; k < 512; k += 256)
            part += b2f(ar[k]) * b2f(br[k]);
    }
    float tot = blk_sum(part, scr);
    if (threadIdx.x == 0) {
        if (t < L_DIM - 1) {
            int ok = mask_ok(allowed, *flag, (size_t)gc * N_DIM + (size_t)gp);
            atomicAdd(&accums[1], ok ? tot : PEN);
        }
        int g0 = min(max(gold[t], 0), N_DIM - 1);
        atomicAdd(&accums[0], U[(size_t)t * N_DIM + g0]);
    }
}

// ===================== log-domain fp32 binary tree ==========================
// C[i][k] = max_j(A[i][j]+B[j][k]) + log(sum_j exp(A[i][j]+B[j][k]-max)).

// Level 1: inputs are pair_k's (E bf16 [i][k], c fp32 [k]); P[i][k]=log(E)+c[k]
__global__ __launch_bounds__(256) void l1comb_k(const u16* __restrict__ Eg,
                                                const float* __restrict__ cvec,
                                                float* __restrict__ Mout,
                                                int n_in) {
    const int o = blockIdx.x, rs = blockIdx.y;
    const int tid = threadIdx.x;
    const u16* E0 = Eg + (size_t)(2 * o) * 16384;
    const float* c0 = cvec + (size_t)(2 * o) * 128;
    float* C = Mout + (size_t)o * 16384;
    if (2 * o + 1 >= n_in) {   // pass-through convert
        for (int idx = tid; idx < 64 * 128; idx += 256) {
            int i = rs * 64 + (idx >> 7), k = idx & 127;
            C[(size_t)i * 128 + k] = loge(E0[(size_t)i * 128 + k]) + c0[k];
        }
        return;
    }
    __shared__ float At[128][64];     // A^T: At[j][i_local] = log E0[i][j] + c0[j]
    __shared__ float Bs[128 * 128];   // B:  Bs[j*128+k]    = log E1[j][k] + c1[k]
    __shared__ float sc0[128], sc1[128];
    const u16* E1 = Eg + (size_t)(2 * o + 1) * 16384;
    const float* c1 = cvec + (size_t)(2 * o + 1) * 128;
    if (tid < 128) { sc0[tid] = c0[tid]; sc1[tid] = c1[tid]; }
    __syncthreads();
    for (int idx = tid; idx < 64 * 128; idx += 256) {
        int il = idx & 63, j = idx >> 6;
        At[j][il] = loge(E0[(size_t)(rs * 64 + il) * 128 + j]) + sc0[j];
    }
    for (int idx = tid; idx < 16384; idx += 256)
        Bs[idx] = loge(E1[idx]) + sc1[idx & 127];
    __syncthreads();
    const int i0 = (tid & 15) * 4, k0 = (tid >> 4) * 8;
    float m[4][8], s[4][8];
#pragma unroll
    for (int a = 0; a < 4; ++a)
#pragma unroll
        for (int b = 0; b < 8; ++b) m[a][b] = -3.0e38f;
    for (int j = 0; j < 128; ++j) {
        float4 av = *(const float4*)&At[j][i0];
        float4 b0 = *(const float4*)&Bs[j * 128 + k0];
        float4 b1 = *(const float4*)&Bs[j * 128 + k0 + 4];
        float aa[4] = {av.x, av.y, av.z, av.w};
        float bb[8] = {b0.x, b0.y, b0.z, b0.w, b1.x, b1.y, b1.z, b1.w};
#pragma unroll
        for (int a = 0; a < 4; ++a)
#pragma unroll
            for (int b = 0; b < 8; ++b) m[a][b] = fmaxf(m[a][b], aa[a] + bb[b]);
    }
#pragma unroll
    for (int a = 0; a < 4; ++a)
#pragma unroll
        for (int b = 0; b < 8; ++b) s[a][b] = 0.f;
    for (int j = 0; j < 128; ++j) {
        float4 av = *(const float4*)&At[j][i0];
        float4 b0 = *(const float4*)&Bs[j * 128 + k0];
        float4 b1 = *(const float4*)&Bs[j * 128 + k0 + 4];
        float aa[4] = {av.x, av.y, av.z, av.w};
        float bb[8] = {b0.x, b0.y, b0.z, b0.w, b1.x, b1.y, b1.z, b1.w};
#pragma unroll
        for (int a = 0; a < 4; ++a)
#pragma unroll
            for (int b = 0; b < 8; ++b) s[a][b] += __expf(aa[a] + bb[b] - m[a][b]);
    }
#pragma unroll
    for (int a = 0; a < 4; ++a)
#pragma unroll
        for (int b = 0; b < 8; ++b)
            C[(size_t)(rs * 64 + i0 + a) * 128 + k0 + b] = m[a][b] + __logf(s[a][b]); // s>=1
}

// Levels 2+: fp32 log matrices in/out
__global__ __launch_bounds__(256) void comb_k(const float* __restrict__ Min,
                                              float* __restrict__ Mout, int n_in) {
    const int o = blockIdx.x, rs = blockIdx.y;
    const int tid = threadIdx.x;
    const float* A = Min + (size_t)(2 * o) * 16384;
    float* C = Mout + (size_t)o * 16384;
    if (2 * o + 1 >= n_in) {
        for (int idx = tid; idx < 64 * 128; idx += 256) {
            int i = rs * 64 + (idx >> 7), k = idx & 127;
            C[(size_t)i * 128 + k] = A[(size_t)i * 128 + k];
        }
        return;
    }
    __shared__ float At[128][64];
    __shared__ float Bs[128 * 128];
    const float* B = Min + (size_t)(2 * o + 1) * 16384;
    for (int idx = tid; idx < 64 * 128; idx += 256) {
        int il = idx & 63, j = idx >> 6;
        At[j][il] = A[(size_t)(rs * 64 + il) * 128 + j];
    }
    for (int idx = tid; idx < 16384; idx += 256) Bs[idx] = B[idx];
    __syncthreads();
    const int i0 = (tid & 15) * 4, k0 = (tid >> 4) * 8;
    float m[4][8], s[4][8];
#pragma unroll
    for (int a = 0; a < 4; ++a)
#pragma unroll
        for (int b = 0; b < 8; ++b) m[a][b] = -3.0e38f;
    for (int j = 0; j < 128; ++j) {
        float4 av = *(const float4*)&At[j][i0];
        float4 b0 = *(const float4*)&Bs[j * 128 + k0];
        float4 b1 = *(const float4*)&Bs[j * 128 + k0 + 4];
        float aa[4] = {av.x, av.y, av.z, av.w};
        float bb[8] = {b0.x, b0.y, b0.z, b0.w, b1.x, b1.y, b1.z, b1.w};
#pragma unroll
        for (int a = 0; a < 4; ++a)
#pragma unroll
            for (int b = 0; b < 8; ++b) m[a][b] = fmaxf(m[a][b], aa[a] + bb[b]);
    }
#pragma unroll
    for (int a = 0; a < 4; ++a)
#pragma unroll
        for (int b = 0; b < 8; ++b) s[a][b] = 0.f;
    for (int j = 0; j < 128; ++j) {
        float4 av = *(const float4*)&At[j][i0];
        float4 b0 = *(const float4*)&Bs[j * 128 + k0];
        float4 b1 = *(const float4*)&Bs[j * 128 + k0 + 4];
        float aa[4] = {av.x, av.y, av.z, av.w};
        float bb[8] = {b0.x, b0.y, b0.z, b0.w, b1.x, b1.y, b1.z, b1.w};
#pragma unroll
        for (int a = 0; a < 4; ++a)
#pragma unroll
            for (int b = 0; b < 8; ++b) s[a][b] += __expf(aa[a] + bb[b] - m[a][b]);
    }
#pragma unroll
    for (int a = 0; a < 4; ++a)
#pragma unroll
        for (int b = 0; b < 8; ++b)
            C[(size_t)(rs * 64 + i0 + a) * 128 + k0 + b] = m[a][b] + __logf(s[a][b]);
}

// -------- final: alpha0 through 32 log-matrices, online LSE, ILP-batched ----
__global__ __launch_bounds__(256) void tfinal_k(const float* __restrict__ M5,
                                                const float* __restrict__ lsmg,
                                                const float* __restrict__ accums,
                                                float* __restrict__ out) {
    __shared__ float v[128];
    __shared__ float pm[2][128], ps[2][128];
    __shared__ float scr[4];
    const int tid = threadIdx.x;
    const int k = tid & 127, h = tid >> 7;
    if (tid < 128) v[tid] = lsmg[tid];   // alpha0
    __syncthreads();
    for (int s = 0; s < 32; ++s) {
        const float* M = M5 + (size_t)s * 16384 + (size_t)h * 64 * 128 + k;
        const float* vh = &v[h * 64];
        float m = -3.0e38f, sum = 0.f;
#pragma unroll 8
        for (int i = 0; i < 64; ++i) {
            float a = vh[i] + M[(size_t)i * 128];
            float nm = fmaxf(m, a);
            sum = sum * __expf(m - nm) + __expf(a - nm);
            m = nm;
        }
        pm[h][k] = m; ps[h][k] = sum;
        __syncthreads();
        if (tid < 128) {
            float m0 = pm[0][tid], m1 = pm[1][tid];
            float mm = fmaxf(m0, m1);
            float ss = ps[0][tid] * __expf(m0 - mm) + ps[1][tid] * __expf(m1 - mm);
            v[tid] = mm + __logf(ss);   // ss >= 1
        }
        __syncthreads();
    }
    float x = (tid < 128) ? v[tid] : -3.0e38f;
    float mz = blk_max(x, scr);
    float e = (tid < 128) ? __expf(v[tid] - mz) : 0.f;
    float sm = blk_sum(e, scr);
    if (tid == 0) out[0] = mz + __logf(fmaxf(sm, 1e-37f)) - (accums[0] + accums[1]);
}

extern "C" void kernel_launch(void* const* d_in, const int* in_sizes, int n_in,
                              void* d_out, int out_size, void* d_ws, size_t ws_size,
                              hipStream_t stream) {
    const float* U = (const float*)d_in[0];
    const float* H = (const float*)d_in[1];
    const float* W = (const float*)d_in[2];
    const int* gold = (const int*)d_in[3];
    const void* allowed = (const void*)d_in[4];

    char* ws = (char*)d_ws;
    float* accums = (float*)ws;            // [0]=score_unary, [1]=score_pair
    int* flag = (int*)(ws + 8);
    size_t off = 256;
    int* cand = (int*)(ws + off);     off += (size_t)L_DIM * R_DIM * 4;
    float* lsm = (float*)(ws + off);  off += (size_t)L_DIM * R_DIM * 4;
    u16* Hbf = (u16*)(ws + off);      off += (size_t)N_DIM * 512 * 2;      // 16 MB
    u16* HWbf = (u16*)(ws + off);     off += (size_t)N_DIM * 512 * 2;      // 16 MB
    u16* E = (u16*)(ws + off);        off += (size_t)(L_DIM - 1) * 16384 * 2; // 32 MB
    float* cvec = (float*)(ws + off); off += (size_t)(L_DIM - 1) * 128 * 4;
    unsigned* bitsw = (unsigned*)(ws + off); off += (size_t)N_DIM * (N_DIM / 8); // 32 MB

    // Tree buffers OVERLAY dead regions:
    // MA (32 MB) = Hbf+HWbf region — dead after score_k, written by L1.
    // MB (16 MB) = E region       — dead after L1 reads it, written by L2.
    float* MA = (float*)Hbf;
    float* MB = (float*)E;

    hipMemsetAsync(d_ws, 0, 256, stream);
    detect_k<<<1, 256, 0, stream>>>((const unsigned*)d_in[4], flag);
    pack_mask_k<<<(int)(((size_t)N_DIM * N_DIM / 32) / 256), 256, 0, stream>>>(allowed, flag, bitsw);
    topk_lsm_k<<<L_DIM, 256, 0, stream>>>(U, cand, lsm);
    cast_h_k<<<(N_DIM * 512) / (256 * 4), 256, 0, stream>>>(H, Hbf);
    gemm_hw_k<<<N_DIM / 8, 256, 0, stream>>>(H, W, HWbf);
    pair_k<<<L_DIM - 1, 256, 0, stream>>>(cand, lsm, HWbf, Hbf, bitsw, E, cvec);
    score_k<<<L_DIM, 256, 0, stream>>>(U, gold, allowed, flag, HWbf, Hbf, accums);
    // binary tree: 1023 -> 512 -> 256 -> 128 -> 64 -> 32, then 32-step scan
    l1comb_k<<<dim3(512, 2), 256, 0, stream>>>(E, cvec, MA, 1023);
    comb_k<<<dim3(256, 2), 256, 0, stream>>>(MA, MB, 512);
    comb_k<<<dim3(128, 2), 256, 0, stream>>>(MB, MA, 256);
    comb_k<<<dim3(64, 2), 256, 0, stream>>>(MA, MB, 128);
    comb_k<<<dim3(32, 2), 256, 0, stream>>>(MB, MA, 64);
    tfinal_k<<<1, 256, 0, stream>>>(MA, lsm, accums, (float*)d_out);
}

// Round 4
// 2036.927 us; speedup vs baseline: 1.4851x; 1.3493x over previous
//
#include <hip/hip_runtime.h>

typedef unsigned short u16;
typedef __attribute__((ext_vector_type(8))) short s8v;
typedef __attribute__((ext_vector_type(8))) __bf16 bfv8;
typedef __attribute__((ext_vector_type(4))) float f32x4;

#define L_DIM 1024
#define N_DIM 16384
#define R_DIM 128
#define PEN  -10000.0f
#define MC_MIN 1e-35f

__device__ __forceinline__ float b2f(u16 x) { return __uint_as_float(((unsigned)x) << 16); }
__device__ __forceinline__ u16 f2bf(float f) {
    unsigned u = __float_as_uint(f);
    unsigned r = (u + 0x7FFFu + ((u >> 16) & 1u)) >> 16;
    return (u16)r;
}
__device__ __forceinline__ unsigned fmapu(float f) {
    unsigned u = __float_as_uint(f);
    return (u & 0x80000000u) ? ~u : (u | 0x80000000u);
}
__device__ __forceinline__ float funmap(unsigned u) {
    unsigned b = (u & 0x80000000u) ? (u & 0x7fffffffu) : ~u;
    return __uint_as_float(b);
}
// flag=0: 4-byte elements (int32 OR float32 bools); flag=1: 1-byte elements
__device__ __forceinline__ int mask_ok(const void* al, int fl, size_t idx) {
    if (fl) return ((const unsigned char*)al)[idx] != 0;
    return ((const unsigned*)al)[idx] != 0u;
}

__device__ __forceinline__ float blk_max(float x, float* scr) {
#pragma unroll
    for (int o = 32; o > 0; o >>= 1) x = fmaxf(x, __shfl_xor(x, o));
    __syncthreads();
    if ((threadIdx.x & 63) == 0) scr[threadIdx.x >> 6] = x;
    __syncthreads();
    return fmaxf(fmaxf(scr[0], scr[1]), fmaxf(scr[2], scr[3]));
}
__device__ __forceinline__ float blk_sum(float x, float* scr) {
#pragma unroll
    for (int o = 32; o > 0; o >>= 1) x += __shfl_xor(x, o);
    __syncthreads();
    if ((threadIdx.x & 63) == 0) scr[threadIdx.x >> 6] = x;
    __syncthreads();
    return scr[0] + scr[1] + scr[2] + scr[3];
}

// -------- detect allowed element width --------------------------------------
__global__ void detect_k(const unsigned* __restrict__ a, int* __restrict__ flag) {
    int bad = 0;
    for (int i = threadIdx.x; i < 4096; i += 256) {
        unsigned w = a[i];
        if (w != 0u && w != 1u && w != 0x3F800000u) bad = 1;
    }
    if (bad) *flag = 1;
}

// -------- bit-pack allowed: bits[cur*512 + (prev>>5)] bit (prev&31) ---------
__global__ __launch_bounds__(256) void pack_mask_k(const void* __restrict__ al,
                                                   const int* __restrict__ flag,
                                                   unsigned* __restrict__ bits) {
    const size_t wi = (size_t)blockIdx.x * 256 + threadIdx.x;  // output word idx
    const int fl = *flag;
    unsigned out = 0u;
    if (fl) {
        const uint4* p = (const uint4*)((const unsigned char*)al + wi * 32);
        uint4 a = p[0], b = p[1];
        unsigned v[8] = {a.x, a.y, a.z, a.w, b.x, b.y, b.z, b.w};
#pragma unroll
        for (int q = 0; q < 8; ++q)
#pragma unroll
            for (int e = 0; e < 4; ++e)
                if ((v[q] >> (e * 8)) & 0xFFu) out |= 1u << (q * 4 + e);
    } else {
        const uint4* p = (const uint4*)((const unsigned*)al + wi * 32);
#pragma unroll
        for (int q = 0; q < 8; ++q) {
            uint4 a = p[q];
            if (a.x) out |= 1u << (q * 4 + 0);
            if (a.y) out |= 1u << (q * 4 + 1);
            if (a.z) out |= 1u << (q * 4 + 2);
            if (a.w) out |= 1u << (q * 4 + 3);
        }
    }
    bits[wi] = out;
}

// -------- per-row top-128 (radix select) + log_softmax over the set ---------
__global__ __launch_bounds__(256) void topk_lsm_k(const float* __restrict__ U,
                                                  int* __restrict__ candg,
                                                  float* __restrict__ lsmg) {
    const int t = blockIdx.x;
    const float* row = U + (size_t)t * N_DIM;
    __shared__ unsigned hist[256];
    __shared__ int sel[2];
    __shared__ int cnts[2];
    __shared__ float vals[128];
    __shared__ int inds[128];
    __shared__ float scr[4];
    const int tid = threadIdx.x;
    unsigned prefix = 0;
    int kneed = 128;
    for (int pass = 0; pass < 4; ++pass) {
        const int sh = 24 - pass * 8;
        hist[tid] = 0;
        __syncthreads();
        for (int i = tid; i < N_DIM; i += 256) {
            unsigned u = __float_as_uint(row[i]);
            unsigned k = (u & 0x80000000u) ? ~u : (u | 0x80000000u);
            bool match = (pass == 0) || ((k >> (sh + 8)) == prefix);
            if (match) atomicAdd(&hist[(k >> sh) & 255u], 1u);
        }
        __syncthreads();
        if (tid == 0) {
            int acc = 0, d = 0;
            for (int dig = 255; dig >= 0; --dig) {
                int c = (int)hist[dig];
                if (acc + c >= kneed) { d = dig; break; }
                acc += c;
            }
            sel[0] = d; sel[1] = acc;
        }
        __syncthreads();
        kneed -= sel[1];
        prefix = (prefix << 8) | (unsigned)sel[0];
        __syncthreads();
    }
    const unsigned K = prefix;
    if (tid < 2) cnts[tid] = 0;
    if (tid < 128) { vals[tid] = -1.0e30f; inds[tid] = 0; }
    __syncthreads();
    for (int i = tid; i < N_DIM; i += 256) {
        float f = row[i];
        unsigned u = __float_as_uint(f);
        unsigned k = (u & 0x80000000u) ? ~u : (u | 0x80000000u);
        if (k > K) { int p = atomicAdd(&cnts[0], 1); if (p < 128) { vals[p] = f; inds[p] = i; } }
    }
    __syncthreads();
    const int cgt = min(cnts[0], 128);
    for (int i = tid; i < N_DIM; i += 256) {
        float f = row[i];
        unsigned u = __float_as_uint(f);
        unsigned k = (u & 0x80000000u) ? ~u : (u | 0x80000000u);
        if (k == K) {
            int p = atomicAdd(&cnts[1], 1);
            if (cgt + p < 128) { vals[cgt + p] = f; inds[cgt + p] = i; }
        }
    }
    __syncthreads();
    float xv = (tid < 128) ? vals[tid] : -3.0e38f;
    float mx = blk_max(xv, scr);
    float ex = (tid < 128) ? __expf(vals[tid] - mx) : 0.f;
    float sm = blk_sum(ex, scr);
    float lse = mx + __logf(fmaxf(sm, 1e-37f));
    if (tid < 128) {
        candg[t * 128 + tid] = min(max(inds[tid], 0), N_DIM - 1);
        lsmg[t * 128 + tid] = vals[tid] - lse;
    }
}

// -------- cast H to bf16 ----------------------------------------------------
__global__ void cast_h_k(const float* __restrict__ H, u16* __restrict__ Hbf) {
    size_t base = ((size_t)blockIdx.x * 256 + threadIdx.x) * 4;
    float4 f = *(const float4*)(H + base);
    ushort4 o;
    o.x = f2bf(f.x); o.y = f2bf(f.y); o.z = f2bf(f.z); o.w = f2bf(f.w);
    *(ushort4*)(Hbf + base) = o;
}

// -------- HW = H @ W (fp32 VALU, bf16 out); 8 rows per block ----------------
__global__ __launch_bounds__(256) void gemm_hw_k(const float* __restrict__ H,
                                                 const float* __restrict__ W,
                                                 u16* __restrict__ HWbf) {
    const int r0 = blockIdx.x * 8;
    __shared__ float Hl[8][512];
    for (int idx = threadIdx.x; idx < 8 * 512; idx += 256) {
        int r = idx >> 9, k = idx & 511;
        Hl[r][k] = H[(size_t)(r0 + r) * 512 + k];
    }
    __syncthreads();
    const int c = threadIdx.x;
    float acc0[8], acc1[8];
#pragma unroll
    for (int r = 0; r < 8; ++r) { acc0[r] = 0.f; acc1[r] = 0.f; }
    for (int k = 0; k < 512; ++k) {
        float w0 = W[(size_t)k * 512 + c];
        float w1 = W[(size_t)k * 512 + c + 256];
#pragma unroll
        for (int r = 0; r < 8; ++r) {
            float h = Hl[r][k];
            acc0[r] += h * w0;
            acc1[r] += h * w1;
        }
    }
#pragma unroll
    for (int r = 0; r < 8; ++r) {
        HWbf[(size_t)(r0 + r) * 512 + c] = f2bf(acc0[r]);
        HWbf[(size_t)(r0 + r) * 512 + c + 256] = f2bf(acc1[r]);
    }
}

// -------- per-step pair matrix via MFMA -> (E row-major bf16, c fp32) -------
// Node rep: P[i][j] = log E[i][j] + cvec[j], E column-normalized (max 1).
// Left-role nodes (even m, m != 1022) are stored pre-scaled:
// E' = E * diag(exp(cvec - g)), with scalar g = max(cvec) in gvec0[m].
__global__ __launch_bounds__(256) void pair_k(const int* __restrict__ candg,
                                              const float* __restrict__ lsmg,
                                              const u16* __restrict__ HWbf,
                                              const u16* __restrict__ Hbf,
                                              const unsigned* __restrict__ bits,
                                              u16* __restrict__ Eg,
                                              float* __restrict__ cvec,
                                              float* __restrict__ gvec0) {
    const int t = blockIdx.x + 1;
    __shared__ __align__(16) u16 tile[2][128 * 64];
    __shared__ int sprev[128], scur[128];
    __shared__ unsigned maskw[128][4];  // maskw[j][i>>5] bit (i&31)
    __shared__ unsigned scm_u[128];
    __shared__ float cmf[128], cvf[128], wvv[128], scr[4];
    const int tid = threadIdx.x;
    if (tid < 128) {
        sprev[tid] = min(max(candg[(t - 1) * 128 + tid], 0), N_DIM - 1);
        scur[tid]  = min(max(candg[t * 128 + tid], 0), N_DIM - 1);
        scm_u[tid] = 0u;
    }
    __syncthreads();

    const int lane = tid & 63, w = tid >> 6;
    const int wr = w >> 1, wc = w & 1;      // wave tile: rows wr*64.., cols wc*64..
    const int srow = lane >> 3, slot = lane & 7;
    const int lq = lane & 15, lh = lane >> 4;

    const u16* pA[4]; const u16* pB[4]; int wadr[4];
#pragma unroll
    for (int q = 0; q < 4; ++q) {
        int r = (w * 4 + q) * 8 + srow;
        pA[q] = HWbf + (size_t)sprev[r] * 512 + slot * 8;
        pB[q] = Hbf  + (size_t)scur[r] * 512 + slot * 8;
        wadr[q] = r * 64 + ((slot ^ srow) * 8);
    }
    s8v rA[4], rB[4];
#pragma unroll
    for (int q = 0; q < 4; ++q) { rA[q] = *(const s8v*)pA[q]; rB[q] = *(const s8v*)pB[q]; }

    // mask gather from bit-packed allowed (L3-resident); overlaps staging latency
    {
        const int j = tid & 127, ihalf = tid >> 7;
        const unsigned* rowp = bits + (size_t)scur[j] * 512;
        unsigned mw0 = 0u, mw1 = 0u;
#pragma unroll 8
        for (int kb = 0; kb < 32; ++kb) {
            int p0 = sprev[ihalf * 64 + kb];
            int p1 = sprev[ihalf * 64 + 32 + kb];
            mw0 |= ((rowp[p0 >> 5] >> (p0 & 31)) & 1u) << kb;
            mw1 |= ((rowp[p1 >> 5] >> (p1 & 31)) & 1u) << kb;
        }
        maskw[j][ihalf * 2]     = mw0;
        maskw[j][ihalf * 2 + 1] = mw1;
    }

    f32x4 acc[4][4];
#pragma unroll
    for (int a = 0; a < 4; ++a)
#pragma unroll
        for (int b = 0; b < 4; ++b) acc[a][b] = (f32x4){0.f, 0.f, 0.f, 0.f};

    for (int s = 0; s < 8; ++s) {
        __syncthreads();
#pragma unroll
        for (int q = 0; q < 4; ++q) {
            *(s8v*)&tile[0][wadr[q]] = rA[q];
            *(s8v*)&tile[1][wadr[q]] = rB[q];
        }
        __syncthreads();
        if (s < 7) {
#pragma unroll
            for (int q = 0; q < 4; ++q) {
                pA[q] += 64; pB[q] += 64;
                rA[q] = *(const s8v*)pA[q];
                rB[q] = *(const s8v*)pB[q];
            }
        }
#pragma unroll
        for (int kk = 0; kk < 2; ++kk) {
            bfv8 aF[4], bF[4];
            const int sl = (((kk << 2) | lh) ^ (lq & 7)) * 8;
#pragma unroll
            for (int b = 0; b < 4; ++b) {
                aF[b] = *(const bfv8*)&tile[0][(wr * 64 + b * 16 + lq) * 64 + sl];
                bF[b] = *(const bfv8*)&tile[1][(wc * 64 + b * 16 + lq) * 64 + sl];
            }
#pragma unroll
            for (int bi = 0; bi < 4; ++bi)
#pragma unroll
                for (int bj = 0; bj < 4; ++bj)
                    acc[bi][bj] = __builtin_amdgcn_mfma_f32_16x16x32_bf16(
                        aF[bi], bF[bj], acc[bi][bj], 0, 0, 0);
        }
    }

    // epilogue: mask, per-column (j) max over i, exp-normalize
#pragma unroll
    for (int bj = 0; bj < 4; ++bj) {
        const int j = wc * 64 + bj * 16 + lq;
        float cm = -3.0e38f;
#pragma unroll
        for (int bi = 0; bi < 4; ++bi) {
#pragma unroll
            for (int r = 0; r < 4; ++r) {
                int i = wr * 64 + bi * 16 + lh * 4 + r;
                float v = acc[bi][bj][r];
                if (!((maskw[j][i >> 5] >> (i & 31)) & 1u)) v += PEN;
                acc[bi][bj][r] = v;
                cm = fmaxf(cm, v);
            }
        }
        cm = fmaxf(cm, __shfl_xor(cm, 16));
        cm = fmaxf(cm, __shfl_xor(cm, 32));
        if (lane < 16) atomicMax(&scm_u[j], fmapu(cm));
    }
    __syncthreads();
    if (tid < 128) {
        float cm = funmap(scm_u[tid]);
        cmf[tid] = cm;
        float cv = cm + lsmg[(size_t)t * 128 + tid];
        cvf[tid] = cv;
        cvec[(size_t)(t - 1) * 128 + tid] = cv;
    }
    __syncthreads();
    const int m = t - 1;
    const int roleA = ((m & 1) == 0) && (m != 1022);
    float xg = (tid < 128) ? cvf[tid] : -3.0e38f;
    float g = blk_max(xg, scr);
    if (tid == 0) gvec0[m] = g;
    if (tid < 128) wvv[tid] = roleA ? __expf(cvf[tid] - g) : 1.0f;
    __syncthreads();
    // restage E through (now dead) tiles for coalesced stores
    u16* Ebuf = &tile[0][0];                // 16384 u16, contiguous
#pragma unroll
    for (int bj = 0; bj < 4; ++bj) {
        const int j = wc * 64 + bj * 16 + lq;
        const float cm = cmf[j];
        const float wj = wvv[j];
#pragma unroll
        for (int bi = 0; bi < 4; ++bi) {
#pragma unroll
            for (int r = 0; r < 4; ++r) {
                int i = wr * 64 + bi * 16 + lh * 4 + r;
                float e = __expf(acc[bi][bj][r] - cm);   // arg <= 0 by construction
                e = fminf(fmaxf(e, 0.f), 1.0f) * wj;     // scrub, apply role scale
                Ebuf[i * 128 + j] = f2bf(e);
            }
        }
    }
    __syncthreads();
    u16* Eo = Eg + (size_t)(t - 1) * 16384;
    for (int idx = tid; idx < 2048; idx += 256)
        ((s8v*)Eo)[idx] = ((const s8v*)Ebuf)[idx];
}

// -------- gold path scores --------------------------------------------------
__global__ __launch_bounds__(256) void score_k(const float* __restrict__ U,
                                               const int* __restrict__ gold,
                                               const void* __restrict__ allowed,
                                               const int* __restrict__ flag,
                                               const u16* __restrict__ HWbf,
                                               const u16* __restrict__ Hbf,
                                               float* __restrict__ accums) {
    const int t = blockIdx.x;
    __shared__ float scr[4];
    float part = 0.f;
    int gp = 0, gc = 0;
    if (t < L_DIM - 1) {
        gp = min(max(gold[t], 0), N_DIM - 1);
        gc = min(max(gold[t + 1], 0), N_DIM - 1);
        const u16* ar = HWbf + (size_t)gp * 512;
        const u16* br = Hbf + (size_t)gc * 512;
        for (int k = threadIdx.x; k < 512; k += 256)
            part += b2f(ar[k]) * b2f(br[k]);
    }
    float tot = blk_sum(part, scr);
    if (threadIdx.x == 0) {
        if (t < L_DIM - 1) {
            int ok = mask_ok(allowed, *flag, (size_t)gc * N_DIM + (size_t)gp);
            atomicAdd(&accums[1], ok ? tot : PEN);
        }
        int g0 = min(max(gold[t], 0), N_DIM - 1);
        atomicAdd(&accums[0], U[(size_t)t * N_DIM + g0]);
    }
}

// ===================== linear-domain MFMA combine tree ======================
// Combine(A,B): S = A_scaled · B (MFMA, K=128), mc[k]=colmax S,
// c' = cB + gA + log mc, G' = S/mc (bf16, re-scaled by exp(c'-g') if out is
// a left child). Dead columns (mc <= MC_MIN) get G'=0, c'=-1e30 sentinel —
// this bounds rmc <= 1e35 (no inf) and log mc in [-80.6, 4.9] (no +inf),
// cutting the inf->NaN death chain that killed round 2.
__global__ __launch_bounds__(256) void mcomb_k(const u16* __restrict__ Gin,
                                               const float* __restrict__ cin,
                                               const float* __restrict__ gin,
                                               u16* __restrict__ Gout,
                                               float* __restrict__ cout,
                                               float* __restrict__ gout,
                                               int n_in, int last) {
    const int o = blockIdx.x;
    const int tid = threadIdx.x;
    __shared__ __align__(16) u16 As[128 * 136];
    __shared__ __align__(16) u16 BT[128 * 136];
    __shared__ float cb[128], rmc[128], wvv[128], scr[4];
    __shared__ unsigned scm[128];
    const u16* GA = Gin + (size_t)(2 * o) * 16384;
    u16* GO = Gout + (size_t)o * 16384;
    const int roleA = (!last) && ((o & 1) == 0);

    if (2 * o + 1 >= n_in) {   // passthrough (input node is B-role stored)
        if (tid < 128) {
            float cv = cin[(size_t)(2 * o) * 128 + tid];
            cb[tid] = cv;
            cout[(size_t)o * 128 + tid] = cv;
        }
        __syncthreads();
        float xg = (tid < 128) ? cb[tid] : -3.0e38f;
        float gp = blk_max(xg, scr);
        if (tid == 0 && gout) gout[o] = gp;
        if (tid < 128) {
            float d = cb[tid] - gp;
            wvv[tid] = roleA ? ((d > -80.f) ? __expf(d) : 0.f) : 1.0f;
        }
        __syncthreads();
        for (int idx = tid; idx < 2048; idx += 256) {
            s8v vv = ((const s8v*)GA)[idx];
            if (roleA) {
                const int j0 = (idx & 15) * 8;
#pragma unroll
                for (int e = 0; e < 8; ++e)
                    vv[e] = (short)f2bf(b2f((u16)vv[e]) * wvv[j0 + e]);
            }
            ((s8v*)GO)[idx] = vv;
        }
        return;
    }

    const float gA = gin[2 * o];
    const u16* GB = Gin + (size_t)(2 * o + 1) * 16384;
    if (tid < 128) {
        cb[tid] = cin[(size_t)(2 * o + 1) * 128 + tid];
        scm[tid] = 0u;
    }
    __syncthreads();
    // stage: threads 0-127 transpose B row 'tid' into BT; 128-255 copy A rows.
    if (tid < 128) {
        const s8v* src = (const s8v*)(GB + (size_t)tid * 128);
#pragma unroll
        for (int q = 0; q < 16; ++q) {
            s8v v = src[q];
#pragma unroll
            for (int e = 0; e < 8; ++e)
                BT[(q * 8 + e) * 136 + tid] = (u16)v[e];
        }
    } else {
        const int t0 = tid - 128;
#pragma unroll
        for (int q = 0; q < 16; ++q) {
            int gc = q * 128 + t0;
            int r = gc >> 4, qc = gc & 15;
            *(s8v*)&As[r * 136 + qc * 8] = *(const s8v*)(GA + (size_t)r * 128 + qc * 8);
        }
    }
    __syncthreads();

    const int lane = tid & 63, w = tid >> 6;
    const int wr = w >> 1, wc = w & 1;
    const int lq = lane & 15, lh = lane >> 4;
    f32x4 acc[4][4];
#pragma unroll
    for (int a = 0; a < 4; ++a)
#pragma unroll
        for (int b = 0; b < 4; ++b) acc[a][b] = (f32x4){0.f, 0.f, 0.f, 0.f};
#pragma unroll
    for (int kc = 0; kc < 4; ++kc) {
        bfv8 aF[4], bF[4];
        const int off = kc * 32 + lh * 8;
#pragma unroll
        for (int b = 0; b < 4; ++b) {
            aF[b] = *(const bfv8*)&As[(wr * 64 + b * 16 + lq) * 136 + off];
            bF[b] = *(const bfv8*)&BT[(wc * 64 + b * 16 + lq) * 136 + off];
        }
#pragma unroll
        for (int bi = 0; bi < 4; ++bi)
#pragma unroll
            for (int bj = 0; bj < 4; ++bj)
                acc[bi][bj] = __builtin_amdgcn_mfma_f32_16x16x32_bf16(
                    aF[bi], bF[bj], acc[bi][bj], 0, 0, 0);
    }
    // per-column max of S (S >= 0 so float-bit uint compare is monotone)
#pragma unroll
    for (int bj = 0; bj < 4; ++bj) {
        float cm = 0.f;
#pragma unroll
        for (int bi = 0; bi < 4; ++bi)
#pragma unroll
            for (int r = 0; r < 4; ++r) cm = fmaxf(cm, acc[bi][bj][r]);
        cm = fmaxf(cm, __shfl_xor(cm, 16));
        cm = fmaxf(cm, __shfl_xor(cm, 32));
        if (lane < 16) atomicMax(&scm[wc * 64 + bj * 16 + lq], __float_as_uint(cm));
    }
    __syncthreads();
    float cpv = -3.0e38f;
    if (tid < 128) {
        float mc = __uint_as_float(scm[tid]);
        if (mc > MC_MIN) {
            rmc[tid] = 1.0f / mc;                  // <= 1e35, finite
            cpv = cb[tid] + gA + __logf(mc);       // log mc in [-80.6, 4.9]
            if (!(cpv > -1.0e29f)) cpv = -1.0e30f; // catch sentinel cb / NaN
        } else {
            rmc[tid] = 0.f;                        // dead column
            cpv = -1.0e30f;
        }
        cout[(size_t)o * 128 + tid] = cpv;
    }
    float gp = blk_max(cpv, scr);
    if (tid == 0 && gout) gout[o] = gp;
    if (tid < 128) {
        float d = cpv - gp;
        wvv[tid] = roleA ? ((d > -80.f) ? __expf(d) : 0.f) : 1.0f;
    }
    __syncthreads();
    // G' = S * rmc (* wv if left-role) -> As (reuse) -> global, coalesced
#pragma unroll
    for (int bj = 0; bj < 4; ++bj) {
        const int k = wc * 64 + bj * 16 + lq;
        const float sc = rmc[k] * wvv[k];
#pragma unroll
        for (int bi = 0; bi < 4; ++bi)
#pragma unroll
            for (int r = 0; r < 4; ++r) {
                const int i = wr * 64 + bi * 16 + lh * 4 + r;
                float e = acc[bi][bj][r] * sc;
                e = fminf(fmaxf(e, 0.f), 1.0f);     // scrub NaN/overshoot
                As[i * 136 + k] = f2bf(e);
            }
    }
    __syncthreads();
    for (int idx = tid; idx < 2048; idx += 256) {
        int r = idx >> 4, qc = idx & 15;
        *(s8v*)(GO + (size_t)r * 128 + qc * 8) = *(const s8v*)&As[r * 136 + qc * 8];
    }
}

// -------- final: alpha0 through 32 (G,c) nodes, linear dot per step ---------
__global__ __launch_bounds__(256) void tfinal2_k(const u16* __restrict__ G5,
                                                 const float* __restrict__ c5,
                                                 const float* __restrict__ lsmg,
                                                 const float* __restrict__ accums,
                                                 float* __restrict__ out) {
    __shared__ float v[128], ev[128], scr[4];
    __shared__ float psum[2][128];
    __shared__ __align__(16) u16 Gs[16384];
    const int tid = threadIdx.x;
    const int k = tid & 127, h = tid >> 7;
    if (tid < 128) v[tid] = lsmg[tid];   // alpha0
    __syncthreads();
    for (int s = 0; s < 32; ++s) {
        const u16* G = G5 + (size_t)s * 16384;
        for (int idx = tid; idx < 2048; idx += 256)
            ((s8v*)Gs)[idx] = ((const s8v*)G)[idx];
        float x = (tid < 128) ? v[tid] : -3.0e38f;
        float mv = blk_max(x, scr);           // internal syncs fence Gs staging
        if (tid < 128) {
            float d = v[tid] - mv;
            ev[tid] = (d > -80.f) ? __expf(d) : 0.f;
        }
        __syncthreads();
        float dot = 0.f;
        const int i0 = h * 64;
#pragma unroll 8
        for (int i = 0; i < 64; ++i)
            dot += ev[i0 + i] * b2f(Gs[(i0 + i) * 128 + k]);
        psum[h][k] = dot;
        __syncthreads();
        if (tid < 128) {
            float d = psum[0][tid] + psum[1][tid];
            v[tid] = (d > 0.f) ? (c5[s * 128 + tid] + mv + __logf(d)) : -1.0e30f;
        }
        __syncthreads();
    }
    float x = (tid < 128) ? v[tid] : -3.0e38f;
    float mz = blk_max(x, scr);
    float e = (tid < 128) ? __expf(v[tid] - mz) : 0.f;
    float sm = blk_sum(e, scr);
    if (tid == 0) out[0] = mz + __logf(fmaxf(sm, 1e-37f)) - (accums[0] + accums[1]);
}

extern "C" void kernel_launch(void* const* d_in, const int* in_sizes, int n_in,
                              void* d_out, int out_size, void* d_ws, size_t ws_size,
                              hipStream_t stream) {
    const float* U = (const float*)d_in[0];
    const float* H = (const float*)d_in[1];
    const float* W = (const float*)d_in[2];
    const int* gold = (const int*)d_in[3];
    const void* allowed = (const void*)d_in[4];

    char* ws = (char*)d_ws;
    float* accums = (float*)ws;            // [0]=score_unary, [1]=score_pair
    int* flag = (int*)(ws + 8);
    size_t off = 256;
    int* cand = (int*)(ws + off);     off += (size_t)L_DIM * R_DIM * 4;
    float* lsm = (float*)(ws + off);  off += (size_t)L_DIM * R_DIM * 4;
    u16* Hbf = (u16*)(ws + off);      off += (size_t)N_DIM * 512 * 2;      // 16 MB
    u16* HWbf = (u16*)(ws + off);     off += (size_t)N_DIM * 512 * 2;      // 16 MB
    u16* E = (u16*)(ws + off);        off += (size_t)(L_DIM - 1) * 16384 * 2; // 32 MB
    float* cvec = (float*)(ws + off); off += (size_t)(L_DIM - 1) * 128 * 4;
    unsigned* bitsw = (unsigned*)(ws + off); off += (size_t)N_DIM * (N_DIM / 8); // 32 MB
    float* gvec0 = (float*)(ws + off); off += 1024 * 4;
    float* c1 = (float*)(ws + off); off += 512 * 128 * 4;
    float* g1 = (float*)(ws + off); off += 512 * 4;
    float* c2 = (float*)(ws + off); off += 256 * 128 * 4;
    float* g2 = (float*)(ws + off); off += 256 * 4;
    float* c3 = (float*)(ws + off); off += 128 * 128 * 4;
    float* g3 = (float*)(ws + off); off += 128 * 4;
    float* c4 = (float*)(ws + off); off += 64 * 128 * 4;
    float* g4 = (float*)(ws + off); off += 64 * 4;
    float* c5 = (float*)(ws + off); off += 32 * 128 * 4;

    // G-level buffers overlay dead bf16 regions (dead after score_k):
    // L1 out: Hbf (512*32KB = 16MB exact); L2: HWbf (8MB); L3: Hbf (4MB);
    // L4: HWbf (2MB); L5: Hbf (1MB). Each level's input is dead when its
    // region is overwritten two levels later.
    u16* G1 = Hbf;
    u16* G2 = HWbf;
    u16* G3 = Hbf;
    u16* G4 = HWbf;
    u16* G5 = Hbf;

    hipMemsetAsync(d_ws, 0, 256, stream);
    detect_k<<<1, 256, 0, stream>>>((const unsigned*)d_in[4], flag);
    pack_mask_k<<<(int)(((size_t)N_DIM * N_DIM / 32) / 256), 256, 0, stream>>>(allowed, flag, bitsw);
    topk_lsm_k<<<L_DIM, 256, 0, stream>>>(U, cand, lsm);
    cast_h_k<<<(N_DIM * 512) / (256 * 4), 256, 0, stream>>>(H, Hbf);
    gemm_hw_k<<<N_DIM / 8, 256, 0, stream>>>(H, W, HWbf);
    pair_k<<<L_DIM - 1, 256, 0, stream>>>(cand, lsm, HWbf, Hbf, bitsw, E, cvec, gvec0);
    score_k<<<L_DIM, 256, 0, stream>>>(U, gold, allowed, flag, HWbf, Hbf, accums);
    // MFMA binary tree: 1023 -> 512 -> 256 -> 128 -> 64 -> 32, then 32-step scan
    mcomb_k<<<512, 256, 0, stream>>>(E, cvec, gvec0, G1, c1, g1, 1023, 0);
    mcomb_k<<<256, 256, 0, stream>>>(G1, c1, g1, G2, c2, g2, 512, 0);
    mcomb_k<<<128, 256, 0, stream>>>(G2, c2, g2, G3, c3, g3, 256, 0);
    mcomb_k<<<64, 256, 0, stream>>>(G3, c3, g3, G4, c4, g4, 128, 0);
    mcomb_k<<<32, 256, 0, stream>>>(G4, c4, g4, G5, c5, (float*)0, 64, 1);
    tfinal2_k<<<1, 256, 0, stream>>>(G5, c5, lsm, accums, (float*)d_out);
}

// Round 5
// 1918.280 us; speedup vs baseline: 1.5770x; 1.0619x over previous
//
#include <hip/hip_runtime.h>

typedef unsigned short u16;
typedef __attribute__((ext_vector_type(8))) short s8v;
typedef __attribute__((ext_vector_type(8))) __bf16 bfv8;
typedef __attribute__((ext_vector_type(4))) float f32x4;

#define L_DIM 1024
#define N_DIM 16384
#define R_DIM 128
#define PEN  -10000.0f
#define MC_MIN 1e-35f

__device__ __forceinline__ float b2f(u16 x) { return __uint_as_float(((unsigned)x) << 16); }
__device__ __forceinline__ u16 f2bf(float f) {
    unsigned u = __float_as_uint(f);
    unsigned r = (u + 0x7FFFu + ((u >> 16) & 1u)) >> 16;
    return (u16)r;
}
__device__ __forceinline__ unsigned fmapu(float f) {
    unsigned u = __float_as_uint(f);
    return (u & 0x80000000u) ? ~u : (u | 0x80000000u);
}
__device__ __forceinline__ float funmap(unsigned u) {
    unsigned b = (u & 0x80000000u) ? (u & 0x7fffffffu) : ~u;
    return __uint_as_float(b);
}
// flag=0: 4-byte elements (int32 OR float32 bools); flag=1: 1-byte elements
__device__ __forceinline__ int mask_ok(const void* al, int fl, size_t idx) {
    if (fl) return ((const unsigned char*)al)[idx] != 0;
    return ((const unsigned*)al)[idx] != 0u;
}

__device__ __forceinline__ float blk_max(float x, float* scr) {
#pragma unroll
    for (int o = 32; o > 0; o >>= 1) x = fmaxf(x, __shfl_xor(x, o));
    __syncthreads();
    if ((threadIdx.x & 63) == 0) scr[threadIdx.x >> 6] = x;
    __syncthreads();
    return fmaxf(fmaxf(scr[0], scr[1]), fmaxf(scr[2], scr[3]));
}
__device__ __forceinline__ float blk_sum(float x, float* scr) {
#pragma unroll
    for (int o = 32; o > 0; o >>= 1) x += __shfl_xor(x, o);
    __syncthreads();
    if ((threadIdx.x & 63) == 0) scr[threadIdx.x >> 6] = x;
    __syncthreads();
    return scr[0] + scr[1] + scr[2] + scr[3];
}

// -------- detect allowed element width --------------------------------------
__global__ void detect_k(const unsigned* __restrict__ a, int* __restrict__ flag) {
    int bad = 0;
    for (int i = threadIdx.x; i < 4096; i += 256) {
        unsigned w = a[i];
        if (w != 0u && w != 1u && w != 0x3F800000u) bad = 1;
    }
    if (bad) *flag = 1;
}

// -------- bit-pack allowed: bits[cur*512 + (prev>>5)] bit (prev&31) ---------
__global__ __launch_bounds__(256) void pack_mask_k(const void* __restrict__ al,
                                                   const int* __restrict__ flag,
                                                   unsigned* __restrict__ bits) {
    const size_t wi = (size_t)blockIdx.x * 256 + threadIdx.x;  // output word idx
    const int fl = *flag;
    unsigned out = 0u;
    if (fl) {
        const uint4* p = (const uint4*)((const unsigned char*)al + wi * 32);
        uint4 a = p[0], b = p[1];
        unsigned v[8] = {a.x, a.y, a.z, a.w, b.x, b.y, b.z, b.w};
#pragma unroll
        for (int q = 0; q < 8; ++q)
#pragma unroll
            for (int e = 0; e < 4; ++e)
                if ((v[q] >> (e * 8)) & 0xFFu) out |= 1u << (q * 4 + e);
    } else {
        const uint4* p = (const uint4*)((const unsigned*)al + wi * 32);
#pragma unroll
        for (int q = 0; q < 8; ++q) {
            uint4 a = p[q];
            if (a.x) out |= 1u << (q * 4 + 0);
            if (a.y) out |= 1u << (q * 4 + 1);
            if (a.z) out |= 1u << (q * 4 + 2);
            if (a.w) out |= 1u << (q * 4 + 3);
        }
    }
    bits[wi] = out;
}

// -------- per-row top-128 (radix select) + log_softmax over the set ---------
// hist is per-wave (4x256) — N(0,1) keys concentrate the top byte into a few
// bins; a shared histogram serializes all 4 waves' atomics on one address.
__global__ __launch_bounds__(256) void topk_lsm_k(const float* __restrict__ U,
                                                  int* __restrict__ candg,
                                                  float* __restrict__ lsmg) {
    const int t = blockIdx.x;
    const float* row = U + (size_t)t * N_DIM;
    __shared__ unsigned hist[4][256];
    __shared__ int sel[2];
    __shared__ int cnts[2];
    __shared__ float vals[128];
    __shared__ int inds[128];
    __shared__ float scr[4];
    const int tid = threadIdx.x;
    const int wv = tid >> 6;
    unsigned prefix = 0;
    int kneed = 128;
    for (int pass = 0; pass < 4; ++pass) {
        const int sh = 24 - pass * 8;
        for (int b = tid; b < 1024; b += 256) ((unsigned*)hist)[b] = 0;
        __syncthreads();
        for (int i = tid; i < N_DIM; i += 256) {
            unsigned u = __float_as_uint(row[i]);
            unsigned k = (u & 0x80000000u) ? ~u : (u | 0x80000000u);
            bool match = (pass == 0) || ((k >> (sh + 8)) == prefix);
            if (match) atomicAdd(&hist[wv][(k >> sh) & 255u], 1u);
        }
        __syncthreads();
        if (tid < 256) hist[0][tid] += hist[1][tid] + hist[2][tid] + hist[3][tid];
        __syncthreads();
        if (tid == 0) {
            int acc = 0, d = 0;
            for (int dig = 255; dig >= 0; --dig) {
                int c = (int)hist[0][dig];
                if (acc + c >= kneed) { d = dig; break; }
                acc += c;
            }
            sel[0] = d; sel[1] = acc;
        }
        __syncthreads();
        kneed -= sel[1];
        prefix = (prefix << 8) | (unsigned)sel[0];
        __syncthreads();
    }
    const unsigned K = prefix;
    if (tid < 2) cnts[tid] = 0;
    if (tid < 128) { vals[tid] = -1.0e30f; inds[tid] = 0; }
    __syncthreads();
    for (int i = tid; i < N_DIM; i += 256) {
        float f = row[i];
        unsigned u = __float_as_uint(f);
        unsigned k = (u & 0x80000000u) ? ~u : (u | 0x80000000u);
        if (k > K) { int p = atomicAdd(&cnts[0], 1); if (p < 128) { vals[p] = f; inds[p] = i; } }
    }
    __syncthreads();
    const int cgt = min(cnts[0], 128);
    for (int i = tid; i < N_DIM; i += 256) {
        float f = row[i];
        unsigned u = __float_as_uint(f);
        unsigned k = (u & 0x80000000u) ? ~u : (u | 0x80000000u);
        if (k == K) {
            int p = atomicAdd(&cnts[1], 1);
            if (cgt + p < 128) { vals[cgt + p] = f; inds[cgt + p] = i; }
        }
    }
    __syncthreads();
    float xv = (tid < 128) ? vals[tid] : -3.0e38f;
    float mx = blk_max(xv, scr);
    float ex = (tid < 128) ? __expf(vals[tid] - mx) : 0.f;
    float sm = blk_sum(ex, scr);
    float lse = mx + __logf(fmaxf(sm, 1e-37f));
    if (tid < 128) {
        candg[t * 128 + tid] = min(max(inds[tid], 0), N_DIM - 1);
        lsmg[t * 128 + tid] = vals[tid] - lse;
    }
}

// -------- cast H to bf16 ----------------------------------------------------
__global__ void cast_h_k(const float* __restrict__ H, u16* __restrict__ Hbf) {
    size_t base = ((size_t)blockIdx.x * 256 + threadIdx.x) * 4;
    float4 f = *(const float4*)(H + base);
    ushort4 o;
    o.x = f2bf(f.x); o.y = f2bf(f.y); o.z = f2bf(f.z); o.w = f2bf(f.w);
    *(ushort4*)(Hbf + base) = o;
}

// -------- cast W^T to bf16 (for MFMA B-operand rows) ------------------------
// Reads are column-gathers of the 1 MB L2-resident W; writes coalesced.
__global__ __launch_bounds__(256) void cast_wT_k(const float* __restrict__ W,
                                                 u16* __restrict__ WT) {
    const int c = blockIdx.x;
    for (int k = threadIdx.x; k < 512; k += 256)
        WT[(size_t)c * 512 + k] = f2bf(W[(size_t)k * 512 + c]);
}

// -------- HW = Hbf @ Wbf via MFMA (replaces VALU gemm_hw) -------------------
// Same staging/fragment/MFMA structure as the validated pair_k, but with
// consecutive rows (no gather), no mask, no softmax. 512 blocks of 128x128.
__global__ __launch_bounds__(256) void gemm_hw2_k(const u16* __restrict__ Hbf,
                                                  const u16* __restrict__ WT,
                                                  u16* __restrict__ HWbf) {
    const int bm = blockIdx.x >> 2, bn = blockIdx.x & 3;
    const int r0 = bm * 128, c0 = bn * 128;
    __shared__ __align__(16) u16 tile[2][128 * 64];
    const int tid = threadIdx.x;
    const int lane = tid & 63, w = tid >> 6;
    const int wr = w >> 1, wc = w & 1;
    const int srow = lane >> 3, slot = lane & 7;
    const int lq = lane & 15, lh = lane >> 4;

    const u16* pA[4]; const u16* pB[4]; int wadr[4];
#pragma unroll
    for (int q = 0; q < 4; ++q) {
        int r = (w * 4 + q) * 8 + srow;
        pA[q] = Hbf + (size_t)(r0 + r) * 512 + slot * 8;
        pB[q] = WT  + (size_t)(c0 + r) * 512 + slot * 8;
        wadr[q] = r * 64 + ((slot ^ srow) * 8);
    }
    s8v rA[4], rB[4];
#pragma unroll
    for (int q = 0; q < 4; ++q) { rA[q] = *(const s8v*)pA[q]; rB[q] = *(const s8v*)pB[q]; }

    f32x4 acc[4][4];
#pragma unroll
    for (int a = 0; a < 4; ++a)
#pragma unroll
        for (int b = 0; b < 4; ++b) acc[a][b] = (f32x4){0.f, 0.f, 0.f, 0.f};

    for (int s = 0; s < 8; ++s) {
        __syncthreads();
#pragma unroll
        for (int q = 0; q < 4; ++q) {
            *(s8v*)&tile[0][wadr[q]] = rA[q];
            *(s8v*)&tile[1][wadr[q]] = rB[q];
        }
        __syncthreads();
        if (s < 7) {
#pragma unroll
            for (int q = 0; q < 4; ++q) {
                pA[q] += 64; pB[q] += 64;
                rA[q] = *(const s8v*)pA[q];
                rB[q] = *(const s8v*)pB[q];
            }
        }
#pragma unroll
        for (int kk = 0; kk < 2; ++kk) {
            bfv8 aF[4], bF[4];
            const int sl = (((kk << 2) | lh) ^ (lq & 7)) * 8;
#pragma unroll
            for (int b = 0; b < 4; ++b) {
                aF[b] = *(const bfv8*)&tile[0][(wr * 64 + b * 16 + lq) * 64 + sl];
                bF[b] = *(const bfv8*)&tile[1][(wc * 64 + b * 16 + lq) * 64 + sl];
            }
#pragma unroll
            for (int bi = 0; bi < 4; ++bi)
#pragma unroll
                for (int bj = 0; bj < 4; ++bj)
                    acc[bi][bj] = __builtin_amdgcn_mfma_f32_16x16x32_bf16(
                        aF[bi], bF[bj], acc[bi][bj], 0, 0, 0);
        }
    }
#pragma unroll
    for (int bj = 0; bj < 4; ++bj) {
        const int j = wc * 64 + bj * 16 + lq;
#pragma unroll
        for (int bi = 0; bi < 4; ++bi)
#pragma unroll
            for (int r = 0; r < 4; ++r) {
                const int i = wr * 64 + bi * 16 + lh * 4 + r;
                HWbf[(size_t)(r0 + i) * 512 + c0 + j] = f2bf(acc[bi][bj][r]);
            }
    }
}

// -------- per-step pair matrix via MFMA -> (E row-major bf16, c fp32) -------
// Node rep: P[i][j] = log E[i][j] + cvec[j], E column-normalized (max 1).
// Left-role nodes (even m, m != 1022) are stored pre-scaled:
// E' = E * diag(exp(cvec - g)), with scalar g = max(cvec) in gvec0[m].
__global__ __launch_bounds__(256) void pair_k(const int* __restrict__ candg,
                                              const float* __restrict__ lsmg,
                                              const u16* __restrict__ HWbf,
                                              const u16* __restrict__ Hbf,
                                              const unsigned* __restrict__ bits,
                                              u16* __restrict__ Eg,
                                              float* __restrict__ cvec,
                                              float* __restrict__ gvec0) {
    const int t = blockIdx.x + 1;
    __shared__ __align__(16) u16 tile[2][128 * 64];
    __shared__ int sprev[128], scur[128];
    __shared__ unsigned maskw[128][4];  // maskw[j][i>>5] bit (i&31)
    __shared__ unsigned scm_u[128];
    __shared__ float cmf[128], cvf[128], wvv[128], scr[4];
    const int tid = threadIdx.x;
    if (tid < 128) {
        sprev[tid] = min(max(candg[(t - 1) * 128 + tid], 0), N_DIM - 1);
        scur[tid]  = min(max(candg[t * 128 + tid], 0), N_DIM - 1);
        scm_u[tid] = 0u;
    }
    __syncthreads();

    const int lane = tid & 63, w = tid >> 6;
    const int wr = w >> 1, wc = w & 1;      // wave tile: rows wr*64.., cols wc*64..
    const int srow = lane >> 3, slot = lane & 7;
    const int lq = lane & 15, lh = lane >> 4;

    const u16* pA[4]; const u16* pB[4]; int wadr[4];
#pragma unroll
    for (int q = 0; q < 4; ++q) {
        int r = (w * 4 + q) * 8 + srow;
        pA[q] = HWbf + (size_t)sprev[r] * 512 + slot * 8;
        pB[q] = Hbf  + (size_t)scur[r] * 512 + slot * 8;
        wadr[q] = r * 64 + ((slot ^ srow) * 8);
    }
    s8v rA[4], rB[4];
#pragma unroll
    for (int q = 0; q < 4; ++q) { rA[q] = *(const s8v*)pA[q]; rB[q] = *(const s8v*)pB[q]; }

    // mask gather from bit-packed allowed (L3-resident); overlaps staging latency
    {
        const int j = tid & 127, ihalf = tid >> 7;
        const unsigned* rowp = bits + (size_t)scur[j] * 512;
        unsigned mw0 = 0u, mw1 = 0u;
#pragma unroll 8
        for (int kb = 0; kb < 32; ++kb) {
            int p0 = sprev[ihalf * 64 + kb];
            int p1 = sprev[ihalf * 64 + 32 + kb];
            mw0 |= ((rowp[p0 >> 5] >> (p0 & 31)) & 1u) << kb;
            mw1 |= ((rowp[p1 >> 5] >> (p1 & 31)) & 1u) << kb;
        }
        maskw[j][ihalf * 2]     = mw0;
        maskw[j][ihalf * 2 + 1] = mw1;
    }

    f32x4 acc[4][4];
#pragma unroll
    for (int a = 0; a < 4; ++a)
#pragma unroll
        for (int b = 0; b < 4; ++b) acc[a][b] = (f32x4){0.f, 0.f, 0.f, 0.f};

    for (int s = 0; s < 8; ++s) {
        __syncthreads();
#pragma unroll
        for (int q = 0; q < 4; ++q) {
            *(s8v*)&tile[0][wadr[q]] = rA[q];
            *(s8v*)&tile[1][wadr[q]] = rB[q];
        }
        __syncthreads();
        if (s < 7) {
#pragma unroll
            for (int q = 0; q < 4; ++q) {
                pA[q] += 64; pB[q] += 64;
                rA[q] = *(const s8v*)pA[q];
                rB[q] = *(const s8v*)pB[q];
            }
        }
#pragma unroll
        for (int kk = 0; kk < 2; ++kk) {
            bfv8 aF[4], bF[4];
            const int sl = (((kk << 2) | lh) ^ (lq & 7)) * 8;
#pragma unroll
            for (int b = 0; b < 4; ++b) {
                aF[b] = *(const bfv8*)&tile[0][(wr * 64 + b * 16 + lq) * 64 + sl];
                bF[b] = *(const bfv8*)&tile[1][(wc * 64 + b * 16 + lq) * 64 + sl];
            }
#pragma unroll
            for (int bi = 0; bi < 4; ++bi)
#pragma unroll
                for (int bj = 0; bj < 4; ++bj)
                    acc[bi][bj] = __builtin_amdgcn_mfma_f32_16x16x32_bf16(
                        aF[bi], bF[bj], acc[bi][bj], 0, 0, 0);
        }
    }

    // epilogue: mask, per-column (j) max over i, exp-normalize
#pragma unroll
    for (int bj = 0; bj < 4; ++bj) {
        const int j = wc * 64 + bj * 16 + lq;
        float cm = -3.0e38f;
#pragma unroll
        for (int bi = 0; bi < 4; ++bi) {
#pragma unroll
            for (int r = 0; r < 4; ++r) {
                int i = wr * 64 + bi * 16 + lh * 4 + r;
                float v = acc[bi][bj][r];
                if (!((maskw[j][i >> 5] >> (i & 31)) & 1u)) v += PEN;
                acc[bi][bj][r] = v;
                cm = fmaxf(cm, v);
            }
        }
        cm = fmaxf(cm, __shfl_xor(cm, 16));
        cm = fmaxf(cm, __shfl_xor(cm, 32));
        if (lane < 16) atomicMax(&scm_u[j], fmapu(cm));
    }
    __syncthreads();
    if (tid < 128) {
        float cm = funmap(scm_u[tid]);
        cmf[tid] = cm;
        float cv = cm + lsmg[(size_t)t * 128 + tid];
        cvf[tid] = cv;
        cvec[(size_t)(t - 1) * 128 + tid] = cv;
    }
    __syncthreads();
    const int m = t - 1;
    const int roleA = ((m & 1) == 0) && (m != 1022);
    float xg = (tid < 128) ? cvf[tid] : -3.0e38f;
    float g = blk_max(xg, scr);
    if (tid == 0) gvec0[m] = g;
    if (tid < 128) wvv[tid] = roleA ? __expf(cvf[tid] - g) : 1.0f;
    __syncthreads();
    // restage E through (now dead) tiles for coalesced stores
    u16* Ebuf = &tile[0][0];                // 16384 u16, contiguous
#pragma unroll
    for (int bj = 0; bj < 4; ++bj) {
        const int j = wc * 64 + bj * 16 + lq;
        const float cm = cmf[j];
        const float wj = wvv[j];
#pragma unroll
        for (int bi = 0; bi < 4; ++bi) {
#pragma unroll
            for (int r = 0; r < 4; ++r) {
                int i = wr * 64 + bi * 16 + lh * 4 + r;
                float e = __expf(acc[bi][bj][r] - cm);   // arg <= 0 by construction
                e = fminf(fmaxf(e, 0.f), 1.0f) * wj;     // scrub, apply role scale
                Ebuf[i * 128 + j] = f2bf(e);
            }
        }
    }
    __syncthreads();
    u16* Eo = Eg + (size_t)(t - 1) * 16384;
    for (int idx = tid; idx < 2048; idx += 256)
        ((s8v*)Eo)[idx] = ((const s8v*)Ebuf)[idx];
}

// -------- gold path scores --------------------------------------------------
__global__ __launch_bounds__(256) void score_k(const float* __restrict__ U,
                                               const int* __restrict__ gold,
                                               const void* __restrict__ allowed,
                                               const int* __restrict__ flag,
                                               const u16* __restrict__ HWbf,
                                               const u16* __restrict__ Hbf,
                                               float* __restrict__ accums) {
    const int t = blockIdx.x;
    __shared__ float scr[4];
    float part = 0.f;
    int gp = 0, gc = 0;
    if (t < L_DIM - 1) {
        gp = min(max(gold[t], 0), N_DIM - 1);
        gc = min(max(gold[t + 1], 0), N_DIM - 1);
        const u16* ar = HWbf + (size_t)gp * 512;
        const u16* br = Hbf + (size_t)gc * 512;
        for (int k = threadIdx.x; k < 512; k += 256)
            part += b2f(ar[k]) * b2f(br[k]);
    }
    float tot = blk_sum(part, scr);
    if (threadIdx.x == 0) {
        if (t < L_DIM - 1) {
            int ok = mask_ok(allowed, *flag, (size_t)gc * N_DIM + (size_t)gp);
            atomicAdd(&accums[1], ok ? tot : PEN);
        }
        int g0 = min(max(gold[t], 0), N_DIM - 1);
        atomicAdd(&accums[0], U[(size_t)t * N_DIM + g0]);
    }
}

// ===================== linear-domain MFMA combine tree ======================
// Combine(A,B): S = A_scaled · B (MFMA, K=128), mc[k]=colmax S,
// c' = cB + gA + log mc, G' = S/mc (bf16, re-scaled by exp(c'-g') if out is
// a left child). Dead columns (mc <= MC_MIN) get G'=0, c'=-1e30 sentinel.
__global__ __launch_bounds__(256) void mcomb_k(const u16* __restrict__ Gin,
                                               const float* __restrict__ cin,
                                               const float* __restrict__ gin,
                                               u16* __restrict__ Gout,
                                               float* __restrict__ cout,
                                               float* __restrict__ gout,
                                               int n_in, int last) {
    const int o = blockIdx.x;
    const int tid = threadIdx.x;
    __shared__ __align__(16) u16 As[128 * 136];
    __shared__ __align__(16) u16 BT[128 * 136];
    __shared__ float cb[128], rmc[128], wvv[128], scr[4];
    __shared__ unsigned scm[128];
    const u16* GA = Gin + (size_t)(2 * o) * 16384;
    u16* GO = Gout + (size_t)o * 16384;
    const int roleA = (!last) && ((o & 1) == 0);

    if (2 * o + 1 >= n_in) {   // passthrough (input node is B-role stored)
        if (tid < 128) {
            float cv = cin[(size_t)(2 * o) * 128 + tid];
            cb[tid] = cv;
            cout[(size_t)o * 128 + tid] = cv;
        }
        __syncthreads();
        float xg = (tid < 128) ? cb[tid] : -3.0e38f;
        float gp = blk_max(xg, scr);
        if (tid == 0 && gout) gout[o] = gp;
        if (tid < 128) {
            float d = cb[tid] - gp;
            wvv[tid] = roleA ? ((d > -80.f) ? __expf(d) : 0.f) : 1.0f;
        }
        __syncthreads();
        for (int idx = tid; idx < 2048; idx += 256) {
            s8v vv = ((const s8v*)GA)[idx];
            if (roleA) {
                const int j0 = (idx & 15) * 8;
#pragma unroll
                for (int e = 0; e < 8; ++e)
                    vv[e] = (short)f2bf(b2f((u16)vv[e]) * wvv[j0 + e]);
            }
            ((s8v*)GO)[idx] = vv;
        }
        return;
    }

    const float gA = gin[2 * o];
    const u16* GB = Gin + (size_t)(2 * o + 1) * 16384;
    if (tid < 128) {
        cb[tid] = cin[(size_t)(2 * o + 1) * 128 + tid];
        scm[tid] = 0u;
    }
    __syncthreads();
    // stage: threads 0-127 transpose B row 'tid' into BT; 128-255 copy A rows.
    if (tid < 128) {
        const s8v* src = (const s8v*)(GB + (size_t)tid * 128);
#pragma unroll
        for (int q = 0; q < 16; ++q) {
            s8v v = src[q];
#pragma unroll
            for (int e = 0; e < 8; ++e)
                BT[(q * 8 + e) * 136 + tid] = (u16)v[e];
        }
    } else {
        const int t0 = tid - 128;
#pragma unroll
        for (int q = 0; q < 16; ++q) {
            int gc = q * 128 + t0;
            int r = gc >> 4, qc = gc & 15;
            *(s8v*)&As[r * 136 + qc * 8] = *(const s8v*)(GA + (size_t)r * 128 + qc * 8);
        }
    }
    __syncthreads();

    const int lane = tid & 63, w = tid >> 6;
    const int wr = w >> 1, wc = w & 1;
    const int lq = lane & 15, lh = lane >> 4;
    f32x4 acc[4][4];
#pragma unroll
    for (int a = 0; a < 4; ++a)
#pragma unroll
        for (int b = 0; b < 4; ++b) acc[a][b] = (f32x4){0.f, 0.f, 0.f, 0.f};
#pragma unroll
    for (int kc = 0; kc < 4; ++kc) {
        bfv8 aF[4], bF[4];
        const int off = kc * 32 + lh * 8;
#pragma unroll
        for (int b = 0; b < 4; ++b) {
            aF[b] = *(const bfv8*)&As[(wr * 64 + b * 16 + lq) * 136 + off];
            bF[b] = *(const bfv8*)&BT[(wc * 64 + b * 16 + lq) * 136 + off];
        }
#pragma unroll
        for (int bi = 0; bi < 4; ++bi)
#pragma unroll
            for (int bj = 0; bj < 4; ++bj)
                acc[bi][bj] = __builtin_amdgcn_mfma_f32_16x16x32_bf16(
                    aF[bi], bF[bj], acc[bi][bj], 0, 0, 0);
    }
    // per-column max of S (S >= 0 so float-bit uint compare is monotone)
#pragma unroll
    for (int bj = 0; bj < 4; ++bj) {
        float cm = 0.f;
#pragma unroll
        for (int bi = 0; bi < 4; ++bi)
#pragma unroll
            for (int r = 0; r < 4; ++r) cm = fmaxf(cm, acc[bi][bj][r]);
        cm = fmaxf(cm, __shfl_xor(cm, 16));
        cm = fmaxf(cm, __shfl_xor(cm, 32));
        if (lane < 16) atomicMax(&scm[wc * 64 + bj * 16 + lq], __float_as_uint(cm));
    }
    __syncthreads();
    float cpv = -3.0e38f;
    if (tid < 128) {
        float mc = __uint_as_float(scm[tid]);
        if (mc > MC_MIN) {
            rmc[tid] = 1.0f / mc;                  // <= 1e35, finite
            cpv = cb[tid] + gA + __logf(mc);       // log mc in [-80.6, 4.9]
            if (!(cpv > -1.0e29f)) cpv = -1.0e30f; // catch sentinel cb / NaN
        } else {
            rmc[tid] = 0.f;                        // dead column
            cpv = -1.0e30f;
        }
        cout[(size_t)o * 128 + tid] = cpv;
    }
    float gp = blk_max(cpv, scr);
    if (tid == 0 && gout) gout[o] = gp;
    if (tid < 128) {
        float d = cpv - gp;
        wvv[tid] = roleA ? ((d > -80.f) ? __expf(d) : 0.f) : 1.0f;
    }
    __syncthreads();
    // G' = S * rmc (* wv if left-role) -> As (reuse) -> global, coalesced
#pragma unroll
    for (int bj = 0; bj < 4; ++bj) {
        const int k = wc * 64 + bj * 16 + lq;
        const float sc = rmc[k] * wvv[k];
#pragma unroll
        for (int bi = 0; bi < 4; ++bi)
#pragma unroll
            for (int r = 0; r < 4; ++r) {
                const int i = wr * 64 + bi * 16 + lh * 4 + r;
                float e = acc[bi][bj][r] * sc;
                e = fminf(fmaxf(e, 0.f), 1.0f);     // scrub NaN/overshoot
                As[i * 136 + k] = f2bf(e);
            }
    }
    __syncthreads();
    for (int idx = tid; idx < 2048; idx += 256) {
        int r = idx >> 4, qc = idx & 15;
        *(s8v*)(GO + (size_t)r * 128 + qc * 8) = *(const s8v*)&As[r * 136 + qc * 8];
    }
}

// -------- final: alpha0 through 32 (G,c) nodes, linear dot per step ---------
__global__ __launch_bounds__(256) void tfinal2_k(const u16* __restrict__ G5,
                                                 const float* __restrict__ c5,
                                                 const float* __restrict__ lsmg,
                                                 const float* __restrict__ accums,
                                                 float* __restrict__ out) {
    __shared__ float v[128], ev[128], scr[4];
    __shared__ float psum[2][128];
    __shared__ __align__(16) u16 Gs[16384];
    const int tid = threadIdx.x;
    const int k = tid & 127, h = tid >> 7;
    if (tid < 128) v[tid] = lsmg[tid];   // alpha0
    __syncthreads();
    for (int s = 0; s < 32; ++s) {
        const u16* G = G5 + (size_t)s * 16384;
        for (int idx = tid; idx < 2048; idx += 256)
            ((s8v*)Gs)[idx] = ((const s8v*)G)[idx];
        float x = (tid < 128) ? v[tid] : -3.0e38f;
        float mv = blk_max(x, scr);           // internal syncs fence Gs staging
        if (tid < 128) {
            float d = v[tid] - mv;
            ev[tid] = (d > -80.f) ? __expf(d) : 0.f;
        }
        __syncthreads();
        float dot = 0.f;
        const int i0 = h * 64;
#pragma unroll 8
        for (int i = 0; i < 64; ++i)
            dot += ev[i0 + i] * b2f(Gs[(i0 + i) * 128 + k]);
        psum[h][k] = dot;
        __syncthreads();
        if (tid < 128) {
            float d = psum[0][tid] + psum[1][tid];
            v[tid] = (d > 0.f) ? (c5[s * 128 + tid] + mv + __logf(d)) : -1.0e30f;
        }
        __syncthreads();
    }
    float x = (tid < 128) ? v[tid] : -3.0e38f;
    float mz = blk_max(x, scr);
    float e = (tid < 128) ? __expf(v[tid] - mz) : 0.f;
    float sm = blk_sum(e, scr);
    if (tid == 0) out[0] = mz + __logf(fmaxf(sm, 1e-37f)) - (accums[0] + accums[1]);
}

extern "C" void kernel_launch(void* const* d_in, const int* in_sizes, int n_in,
                              void* d_out, int out_size, void* d_ws, size_t ws_size,
                              hipStream_t stream) {
    const float* U = (const float*)d_in[0];
    const float* H = (const float*)d_in[1];
    const float* W = (const float*)d_in[2];
    const int* gold = (const int*)d_in[3];
    const void* allowed = (const void*)d_in[4];

    char* ws = (char*)d_ws;
    float* accums = (float*)ws;            // [0]=score_unary, [1]=score_pair
    int* flag = (int*)(ws + 8);
    size_t off = 256;
    int* cand = (int*)(ws + off);     off += (size_t)L_DIM * R_DIM * 4;
    float* lsm = (float*)(ws + off);  off += (size_t)L_DIM * R_DIM * 4;
    u16* Hbf = (u16*)(ws + off);      off += (size_t)N_DIM * 512 * 2;      // 16 MB
    u16* HWbf = (u16*)(ws + off);     off += (size_t)N_DIM * 512 * 2;      // 16 MB
    u16* E = (u16*)(ws + off);        off += (size_t)(L_DIM - 1) * 16384 * 2; // 32 MB
    float* cvec = (float*)(ws + off); off += (size_t)(L_DIM - 1) * 128 * 4;
    unsigned* bitsw = (unsigned*)(ws + off); off += (size_t)N_DIM * (N_DIM / 8); // 32 MB
    float* gvec0 = (float*)(ws + off); off += 1024 * 4;
    float* c1 = (float*)(ws + off); off += 512 * 128 * 4;
    float* g1 = (float*)(ws + off); off += 512 * 4;
    float* c2 = (float*)(ws + off); off += 256 * 128 * 4;
    float* g2 = (float*)(ws + off); off += 256 * 4;
    float* c3 = (float*)(ws + off); off += 128 * 128 * 4;
    float* g3 = (float*)(ws + off); off += 128 * 4;
    float* c4 = (float*)(ws + off); off += 64 * 128 * 4;
    float* g4 = (float*)(ws + off); off += 64 * 4;
    float* c5 = (float*)(ws + off); off += 32 * 128 * 4;
    u16* WbfT = (u16*)(ws + off);   off += (size_t)512 * 512 * 2;          // 0.5 MB

    // G-level buffers overlay dead bf16 regions (dead after score_k):
    u16* G1 = Hbf;
    u16* G2 = HWbf;
    u16* G3 = Hbf;
    u16* G4 = HWbf;
    u16* G5 = Hbf;

    hipMemsetAsync(d_ws, 0, 256, stream);
    detect_k<<<1, 256, 0, stream>>>((const unsigned*)d_in[4], flag);
    pack_mask_k<<<(int)(((size_t)N_DIM * N_DIM / 32) / 256), 256, 0, stream>>>(allowed, flag, bitsw);
    topk_lsm_k<<<L_DIM, 256, 0, stream>>>(U, cand, lsm);
    cast_h_k<<<(N_DIM * 512) / (256 * 4), 256, 0, stream>>>(H, Hbf);
    cast_wT_k<<<512, 256, 0, stream>>>(W, WbfT);
    gemm_hw2_k<<<512, 256, 0, stream>>>(Hbf, WbfT, HWbf);
    pair_k<<<L_DIM - 1, 256, 0, stream>>>(cand, lsm, HWbf, Hbf, bitsw, E, cvec, gvec0);
    score_k<<<L_DIM, 256, 0, stream>>>(U, gold, allowed, flag, HWbf, Hbf, accums);
    // MFMA binary tree: 1023 -> 512 -> 256 -> 128 -> 64 -> 32, then 32-step scan
    mcomb_k<<<512, 256, 0, stream>>>(E, cvec, gvec0, G1, c1, g1, 1023, 0);
    mcomb_k<<<256, 256, 0, stream>>>(G1, c1, g1, G2, c2, g2, 512, 0);
    mcomb_k<<<128, 256, 0, stream>>>(G2, c2, g2, G3, c3, g3, 256, 0);
    mcomb_k<<<64, 256, 0, stream>>>(G3, c3, g3, G4, c4, g4, 128, 0);
    mcomb_k<<<32, 256, 0, stream>>>(G4, c4, g4, G5, c5, (float*)0, 64, 1);
    tfinal2_k<<<1, 256, 0, stream>>>(G5, c5, lsm, accums, (float*)d_out);
}

// Round 6
// 1846.313 us; speedup vs baseline: 1.6384x; 1.0390x over previous
//
#include <hip/hip_runtime.h>

typedef unsigned short u16;
typedef __attribute__((ext_vector_type(8))) short s8v;
typedef __attribute__((ext_vector_type(8))) __bf16 bfv8;
typedef __attribute__((ext_vector_type(4))) float f32x4;

#define L_DIM 1024
#define N_DIM 16384
#define R_DIM 128
#define PEN  -10000.0f
#define MC_MIN 1e-35f
#define TCAP 4096

__device__ __forceinline__ float b2f(u16 x) { return __uint_as_float(((unsigned)x) << 16); }
__device__ __forceinline__ u16 f2bf(float f) {
    unsigned u = __float_as_uint(f);
    unsigned r = (u + 0x7FFFu + ((u >> 16) & 1u)) >> 16;
    return (u16)r;
}
__device__ __forceinline__ unsigned fmapu(float f) {
    unsigned u = __float_as_uint(f);
    return (u & 0x80000000u) ? ~u : (u | 0x80000000u);
}
__device__ __forceinline__ float funmap(unsigned u) {
    unsigned b = (u & 0x80000000u) ? (u & 0x7fffffffu) : ~u;
    return __uint_as_float(b);
}
// flag=0: 4-byte elements (int32 OR float32 bools); flag=1: 1-byte elements
__device__ __forceinline__ int mask_ok(const void* al, int fl, size_t idx) {
    if (fl) return ((const unsigned char*)al)[idx] != 0;
    return ((const unsigned*)al)[idx] != 0u;
}

__device__ __forceinline__ float blk_max(float x, float* scr) {
#pragma unroll
    for (int o = 32; o > 0; o >>= 1) x = fmaxf(x, __shfl_xor(x, o));
    __syncthreads();
    if ((threadIdx.x & 63) == 0) scr[threadIdx.x >> 6] = x;
    __syncthreads();
    return fmaxf(fmaxf(scr[0], scr[1]), fmaxf(scr[2], scr[3]));
}
__device__ __forceinline__ float blk_sum(float x, float* scr) {
#pragma unroll
    for (int o = 32; o > 0; o >>= 1) x += __shfl_xor(x, o);
    __syncthreads();
    if ((threadIdx.x & 63) == 0) scr[threadIdx.x >> 6] = x;
    __syncthreads();
    return scr[0] + scr[1] + scr[2] + scr[3];
}

// -------- detect allowed element width --------------------------------------
__global__ void detect_k(const unsigned* __restrict__ a, int* __restrict__ flag) {
    int bad = 0;
    for (int i = threadIdx.x; i < 4096; i += 256) {
        unsigned w = a[i];
        if (w != 0u && w != 1u && w != 0x3F800000u) bad = 1;
    }
    if (bad) *flag = 1;
}

// -------- bit-pack allowed: bits[cur*512 + (prev>>5)] bit (prev&31) ---------
__global__ __launch_bounds__(256) void pack_mask_k(const void* __restrict__ al,
                                                   const int* __restrict__ flag,
                                                   unsigned* __restrict__ bits) {
    const size_t wi = (size_t)blockIdx.x * 256 + threadIdx.x;  // output word idx
    const int fl = *flag;
    unsigned out = 0u;
    if (fl) {
        const uint4* p = (const uint4*)((const unsigned char*)al + wi * 32);
        uint4 a = p[0], b = p[1];
        unsigned v[8] = {a.x, a.y, a.z, a.w, b.x, b.y, b.z, b.w};
#pragma unroll
        for (int q = 0; q < 8; ++q)
#pragma unroll
            for (int e = 0; e < 4; ++e)
                if ((v[q] >> (e * 8)) & 0xFFu) out |= 1u << (q * 4 + e);
    } else {
        const uint4* p = (const uint4*)((const unsigned*)al + wi * 32);
#pragma unroll
        for (int q = 0; q < 8; ++q) {
            uint4 a = p[q];
            if (a.x) out |= 1u << (q * 4 + 0);
            if (a.y) out |= 1u << (q * 4 + 1);
            if (a.z) out |= 1u << (q * 4 + 2);
            if (a.w) out |= 1u << (q * 4 + 3);
        }
    }
    bits[wi] = out;
}

// -------- per-row top-128 (2-global-pass radix select) + log_softmax --------
// Pass A: per-wave byte histogram -> top digit d0 (direct winners byte>d0 are
// <128 by the radix invariant). Pass B: classify row into direct winners +
// LDS candidate buffer (byte==d0; ~400 entries for N(0,1) at R=128). Radix
// passes 1-3 and selection then run on the LDS buffer — 6 global row passes
// become 2. Block-uniform overflow fallback = original global algorithm.
__global__ __launch_bounds__(256) void topk_lsm_k(const float* __restrict__ U,
                                                  int* __restrict__ candg,
                                                  float* __restrict__ lsmg) {
    const int t = blockIdx.x;
    const float* row = U + (size_t)t * N_DIM;
    __shared__ unsigned hist[4][256];
    __shared__ unsigned keybuf[TCAP];
    __shared__ u16 idxbuf[TCAP];
    __shared__ unsigned dirk[128];
    __shared__ u16 diri[128];
    __shared__ int sel[2];
    __shared__ int nums[2];     // [0]=ndir, [1]=nbuf
    __shared__ int cnts[2];
    __shared__ float vals[128];
    __shared__ int inds[128];
    __shared__ float scr[4];
    const int tid = threadIdx.x;
    const int wv = tid >> 6;

    // pass A: byte histogram (per-wave to avoid hot-bin cross-wave serialization)
    for (int b = tid; b < 1024; b += 256) ((unsigned*)hist)[b] = 0;
    if (tid < 2) { nums[tid] = 0; cnts[tid] = 0; }
    if (tid < 128) { vals[tid] = -1.0e30f; inds[tid] = 0; }
    __syncthreads();
    for (int i = tid; i < N_DIM; i += 256) {
        unsigned u = __float_as_uint(row[i]);
        unsigned k = (u & 0x80000000u) ? ~u : (u | 0x80000000u);
        atomicAdd(&hist[wv][k >> 24], 1u);
    }
    __syncthreads();
    if (tid < 256) hist[0][tid] += hist[1][tid] + hist[2][tid] + hist[3][tid];
    __syncthreads();
    if (tid == 0) {
        int acc = 0, d = 0;
        for (int dig = 255; dig >= 0; --dig) {
            int c = (int)hist[0][dig];
            if (acc + c >= 128) { d = dig; break; }
            acc += c;
        }
        sel[0] = d; sel[1] = acc;
    }
    __syncthreads();
    const unsigned d0 = (unsigned)sel[0];
    int kneed = 128 - sel[1];
    unsigned prefix = d0;
    __syncthreads();

    // pass B: classify (direct winner / candidate)
    for (int i = tid; i < N_DIM; i += 256) {
        unsigned u = __float_as_uint(row[i]);
        unsigned k = (u & 0x80000000u) ? ~u : (u | 0x80000000u);
        unsigned by = k >> 24;
        if (by > d0) {
            int p = atomicAdd(&nums[0], 1);
            if (p < 128) { dirk[p] = k; diri[p] = (u16)i; }
        } else if (by == d0) {
            int p = atomicAdd(&nums[1], 1);
            if (p < TCAP) { keybuf[p] = k; idxbuf[p] = (u16)i; }
        }
    }
    __syncthreads();
    const int ndir = min(nums[0], 128);
    const int nbuf = nums[1];

    if (nbuf <= TCAP) {
        // radix passes 1-3 over the LDS candidate buffer
        for (int pass = 1; pass < 4; ++pass) {
            const int sh = 24 - pass * 8;
            if (tid < 256) hist[0][tid] = 0;
            __syncthreads();
            for (int j = tid; j < nbuf; j += 256) {
                unsigned k = keybuf[j];
                if ((k >> (sh + 8)) == prefix) atomicAdd(&hist[0][(k >> sh) & 255u], 1u);
            }
            __syncthreads();
            if (tid == 0) {
                int acc = 0, d = 0;
                for (int dig = 255; dig >= 0; --dig) {
                    int c = (int)hist[0][dig];
                    if (acc + c >= kneed) { d = dig; break; }
                    acc += c;
                }
                sel[0] = d; sel[1] = acc;
            }
            __syncthreads();
            kneed -= sel[1];
            prefix = (prefix << 8) | (unsigned)sel[0];
            __syncthreads();
        }
        const unsigned K = prefix;
        // strictly greater: all direct winners + buffer entries > K
        for (int j = tid; j < ndir; j += 256) {
            int p = atomicAdd(&cnts[0], 1);
            if (p < 128) { vals[p] = funmap(dirk[j]); inds[p] = diri[j]; }
        }
        for (int j = tid; j < nbuf; j += 256) {
            unsigned k = keybuf[j];
            if (k > K) {
                int p = atomicAdd(&cnts[0], 1);
                if (p < 128) { vals[p] = funmap(k); inds[p] = idxbuf[j]; }
            }
        }
        __syncthreads();
        const int cgt = min(cnts[0], 128);
        for (int j = tid; j < nbuf; j += 256) {
            unsigned k = keybuf[j];
            if (k == K) {
                int p = atomicAdd(&cnts[1], 1);
                if (cgt + p < 128) { vals[cgt + p] = funmap(k); inds[cgt + p] = idxbuf[j]; }
            }
        }
        __syncthreads();
    } else {
        // fallback (adversarial key distributions): original global-row passes
        for (int pass = 1; pass < 4; ++pass) {
            const int sh = 24 - pass * 8;
            if (tid < 256) hist[0][tid] = 0;
            __syncthreads();
            for (int i = tid; i < N_DIM; i += 256) {
                unsigned u = __float_as_uint(row[i]);
                unsigned k = (u & 0x80000000u) ? ~u : (u | 0x80000000u);
                if ((k >> (sh + 8)) == prefix) atomicAdd(&hist[0][(k >> sh) & 255u], 1u);
            }
            __syncthreads();
            if (tid == 0) {
                int acc = 0, d = 0;
                for (int dig = 255; dig >= 0; --dig) {
                    int c = (int)hist[0][dig];
                    if (acc + c >= kneed) { d = dig; break; }
                    acc += c;
                }
                sel[0] = d; sel[1] = acc;
            }
            __syncthreads();
            kneed -= sel[1];
            prefix = (prefix << 8) | (unsigned)sel[0];
            __syncthreads();
        }
        const unsigned K = prefix;
        for (int i = tid; i < N_DIM; i += 256) {
            float f = row[i];
            unsigned k = fmapu(f);
            if (k > K) {
                int p = atomicAdd(&cnts[0], 1);
                if (p < 128) { vals[p] = f; inds[p] = i; }
            }
        }
        __syncthreads();
        const int cgt = min(cnts[0], 128);
        for (int i = tid; i < N_DIM; i += 256) {
            float f = row[i];
            unsigned k = fmapu(f);
            if (k == K) {
                int p = atomicAdd(&cnts[1], 1);
                if (cgt + p < 128) { vals[cgt + p] = f; inds[cgt + p] = i; }
            }
        }
        __syncthreads();
    }

    float xv = (tid < 128) ? vals[tid] : -3.0e38f;
    float mx = blk_max(xv, scr);
    float ex = (tid < 128) ? __expf(vals[tid] - mx) : 0.f;
    float sm = blk_sum(ex, scr);
    float lse = mx + __logf(fmaxf(sm, 1e-37f));
    if (tid < 128) {
        candg[t * 128 + tid] = min(max(inds[tid], 0), N_DIM - 1);
        lsmg[t * 128 + tid] = vals[tid] - lse;
    }
}

// -------- cast H to bf16 ----------------------------------------------------
__global__ void cast_h_k(const float* __restrict__ H, u16* __restrict__ Hbf) {
    size_t base = ((size_t)blockIdx.x * 256 + threadIdx.x) * 4;
    float4 f = *(const float4*)(H + base);
    ushort4 o;
    o.x = f2bf(f.x); o.y = f2bf(f.y); o.z = f2bf(f.z); o.w = f2bf(f.w);
    *(ushort4*)(Hbf + base) = o;
}

// -------- cast W^T to bf16 (for MFMA B-operand rows) ------------------------
__global__ __launch_bounds__(256) void cast_wT_k(const float* __restrict__ W,
                                                 u16* __restrict__ WT) {
    const int c = blockIdx.x;
    for (int k = threadIdx.x; k < 512; k += 256)
        WT[(size_t)c * 512 + k] = f2bf(W[(size_t)k * 512 + c]);
}

// -------- HW = Hbf @ Wbf via MFMA -------------------------------------------
__global__ __launch_bounds__(256) void gemm_hw2_k(const u16* __restrict__ Hbf,
                                                  const u16* __restrict__ WT,
                                                  u16* __restrict__ HWbf) {
    const int bm = blockIdx.x >> 2, bn = blockIdx.x & 3;
    const int r0 = bm * 128, c0 = bn * 128;
    __shared__ __align__(16) u16 tile[2][128 * 64];
    const int tid = threadIdx.x;
    const int lane = tid & 63, w = tid >> 6;
    const int wr = w >> 1, wc = w & 1;
    const int srow = lane >> 3, slot = lane & 7;
    const int lq = lane & 15, lh = lane >> 4;

    const u16* pA[4]; const u16* pB[4]; int wadr[4];
#pragma unroll
    for (int q = 0; q < 4; ++q) {
        int r = (w * 4 + q) * 8 + srow;
        pA[q] = Hbf + (size_t)(r0 + r) * 512 + slot * 8;
        pB[q] = WT  + (size_t)(c0 + r) * 512 + slot * 8;
        wadr[q] = r * 64 + ((slot ^ srow) * 8);
    }
    s8v rA[4], rB[4];
#pragma unroll
    for (int q = 0; q < 4; ++q) { rA[q] = *(const s8v*)pA[q]; rB[q] = *(const s8v*)pB[q]; }

    f32x4 acc[4][4];
#pragma unroll
    for (int a = 0; a < 4; ++a)
#pragma unroll
        for (int b = 0; b < 4; ++b) acc[a][b] = (f32x4){0.f, 0.f, 0.f, 0.f};

    for (int s = 0; s < 8; ++s) {
        __syncthreads();
#pragma unroll
        for (int q = 0; q < 4; ++q) {
            *(s8v*)&tile[0][wadr[q]] = rA[q];
            *(s8v*)&tile[1][wadr[q]] = rB[q];
        }
        __syncthreads();
        if (s < 7) {
#pragma unroll
            for (int q = 0; q < 4; ++q) {
                pA[q] += 64; pB[q] += 64;
                rA[q] = *(const s8v*)pA[q];
                rB[q] = *(const s8v*)pB[q];
            }
        }
#pragma unroll
        for (int kk = 0; kk < 2; ++kk) {
            bfv8 aF[4], bF[4];
            const int sl = (((kk << 2) | lh) ^ (lq & 7)) * 8;
#pragma unroll
            for (int b = 0; b < 4; ++b) {
                aF[b] = *(const bfv8*)&tile[0][(wr * 64 + b * 16 + lq) * 64 + sl];
                bF[b] = *(const bfv8*)&tile[1][(wc * 64 + b * 16 + lq) * 64 + sl];
            }
#pragma unroll
            for (int bi = 0; bi < 4; ++bi)
#pragma unroll
                for (int bj = 0; bj < 4; ++bj)
                    acc[bi][bj] = __builtin_amdgcn_mfma_f32_16x16x32_bf16(
                        aF[bi], bF[bj], acc[bi][bj], 0, 0, 0);
        }
    }
#pragma unroll
    for (int bj = 0; bj < 4; ++bj) {
        const int j = wc * 64 + bj * 16 + lq;
#pragma unroll
        for (int bi = 0; bi < 4; ++bi)
#pragma unroll
            for (int r = 0; r < 4; ++r) {
                const int i = wr * 64 + bi * 16 + lh * 4 + r;
                HWbf[(size_t)(r0 + i) * 512 + c0 + j] = f2bf(acc[bi][bj][r]);
            }
    }
}

// -------- per-step pair matrix via MFMA -> (E row-major bf16, c fp32) -------
// Node rep: P[i][j] = log E[i][j] + cvec[j], E column-normalized (max 1).
// Left-role nodes (even m, m != 1022) are stored pre-scaled:
// E' = E * diag(exp(cvec - g)), with scalar g = max(cvec) in gvec0[m].
__global__ __launch_bounds__(256) void pair_k(const int* __restrict__ candg,
                                              const float* __restrict__ lsmg,
                                              const u16* __restrict__ HWbf,
                                              const u16* __restrict__ Hbf,
                                              const unsigned* __restrict__ bits,
                                              u16* __restrict__ Eg,
                                              float* __restrict__ cvec,
                                              float* __restrict__ gvec0) {
    const int t = blockIdx.x + 1;
    __shared__ __align__(16) u16 tile[2][128 * 64];
    __shared__ int sprev[128], scur[128];
    __shared__ unsigned maskw[128][4];  // maskw[j][i>>5] bit (i&31)
    __shared__ unsigned scm_u[128];
    __shared__ float cmf[128], cvf[128], wvv[128], scr[4];
    const int tid = threadIdx.x;
    if (tid < 128) {
        sprev[tid] = min(max(candg[(t - 1) * 128 + tid], 0), N_DIM - 1);
        scur[tid]  = min(max(candg[t * 128 + tid], 0), N_DIM - 1);
        scm_u[tid] = 0u;
    }
    __syncthreads();

    const int lane = tid & 63, w = tid >> 6;
    const int wr = w >> 1, wc = w & 1;      // wave tile: rows wr*64.., cols wc*64..
    const int srow = lane >> 3, slot = lane & 7;
    const int lq = lane & 15, lh = lane >> 4;

    const u16* pA[4]; const u16* pB[4]; int wadr[4];
#pragma unroll
    for (int q = 0; q < 4; ++q) {
        int r = (w * 4 + q) * 8 + srow;
        pA[q] = HWbf + (size_t)sprev[r] * 512 + slot * 8;
        pB[q] = Hbf  + (size_t)scur[r] * 512 + slot * 8;
        wadr[q] = r * 64 + ((slot ^ srow) * 8);
    }
    s8v rA[4], rB[4];
#pragma unroll
    for (int q = 0; q < 4; ++q) { rA[q] = *(const s8v*)pA[q]; rB[q] = *(const s8v*)pB[q]; }

    // mask gather from bit-packed allowed (L3-resident); overlaps staging latency
    {
        const int j = tid & 127, ihalf = tid >> 7;
        const unsigned* rowp = bits + (size_t)scur[j] * 512;
        unsigned mw0 = 0u, mw1 = 0u;
#pragma unroll 8
        for (int kb = 0; kb < 32; ++kb) {
            int p0 = sprev[ihalf * 64 + kb];
            int p1 = sprev[ihalf * 64 + 32 + kb];
            mw0 |= ((rowp[p0 >> 5] >> (p0 & 31)) & 1u) << kb;
            mw1 |= ((rowp[p1 >> 5] >> (p1 & 31)) & 1u) << kb;
        }
        maskw[j][ihalf * 2]     = mw0;
        maskw[j][ihalf * 2 + 1] = mw1;
    }

    f32x4 acc[4][4];
#pragma unroll
    for (int a = 0; a < 4; ++a)
#pragma unroll
        for (int b = 0; b < 4; ++b) acc[a][b] = (f32x4){0.f, 0.f, 0.f, 0.f};

    for (int s = 0; s < 8; ++s) {
        __syncthreads();
#pragma unroll
        for (int q = 0; q < 4; ++q) {
            *(s8v*)&tile[0][wadr[q]] = rA[q];
            *(s8v*)&tile[1][wadr[q]] = rB[q];
        }
        __syncthreads();
        if (s < 7) {
#pragma unroll
            for (int q = 0; q < 4; ++q) {
                pA[q] += 64; pB[q] += 64;
                rA[q] = *(const s8v*)pA[q];
                rB[q] = *(const s8v*)pB[q];
            }
        }
#pragma unroll
        for (int kk = 0; kk < 2; ++kk) {
            bfv8 aF[4], bF[4];
            const int sl = (((kk << 2) | lh) ^ (lq & 7)) * 8;
#pragma unroll
            for (int b = 0; b < 4; ++b) {
                aF[b] = *(const bfv8*)&tile[0][(wr * 64 + b * 16 + lq) * 64 + sl];
                bF[b] = *(const bfv8*)&tile[1][(wc * 64 + b * 16 + lq) * 64 + sl];
            }
#pragma unroll
            for (int bi = 0; bi < 4; ++bi)
#pragma unroll
                for (int bj = 0; bj < 4; ++bj)
                    acc[bi][bj] = __builtin_amdgcn_mfma_f32_16x16x32_bf16(
                        aF[bi], bF[bj], acc[bi][bj], 0, 0, 0);
        }
    }

    // epilogue: mask, per-column (j) max over i, exp-normalize
#pragma unroll
    for (int bj = 0; bj < 4; ++bj) {
        const int j = wc * 64 + bj * 16 + lq;
        float cm = -3.0e38f;
#pragma unroll
        for (int bi = 0; bi < 4; ++bi) {
#pragma unroll
            for (int r = 0; r < 4; ++r) {
                int i = wr * 64 + bi * 16 + lh * 4 + r;
                float v = acc[bi][bj][r];
                if (!((maskw[j][i >> 5] >> (i & 31)) & 1u)) v += PEN;
                acc[bi][bj][r] = v;
                cm = fmaxf(cm, v);
            }
        }
        cm = fmaxf(cm, __shfl_xor(cm, 16));
        cm = fmaxf(cm, __shfl_xor(cm, 32));
        if (lane < 16) atomicMax(&scm_u[j], fmapu(cm));
    }
    __syncthreads();
    if (tid < 128) {
        float cm = funmap(scm_u[tid]);
        cmf[tid] = cm;
        float cv = cm + lsmg[(size_t)t * 128 + tid];
        cvf[tid] = cv;
        cvec[(size_t)(t - 1) * 128 + tid] = cv;
    }
    __syncthreads();
    const int m = t - 1;
    const int roleA = ((m & 1) == 0) && (m != 1022);
    float xg = (tid < 128) ? cvf[tid] : -3.0e38f;
    float g = blk_max(xg, scr);
    if (tid == 0) gvec0[m] = g;
    if (tid < 128) wvv[tid] = roleA ? __expf(cvf[tid] - g) : 1.0f;
    __syncthreads();
    // restage E through (now dead) tiles for coalesced stores
    u16* Ebuf = &tile[0][0];                // 16384 u16, contiguous
#pragma unroll
    for (int bj = 0; bj < 4; ++bj) {
        const int j = wc * 64 + bj * 16 + lq;
        const float cm = cmf[j];
        const float wj = wvv[j];
#pragma unroll
        for (int bi = 0; bi < 4; ++bi) {
#pragma unroll
            for (int r = 0; r < 4; ++r) {
                int i = wr * 64 + bi * 16 + lh * 4 + r;
                float e = __expf(acc[bi][bj][r] - cm);   // arg <= 0 by construction
                e = fminf(fmaxf(e, 0.f), 1.0f) * wj;     // scrub, apply role scale
                Ebuf[i * 128 + j] = f2bf(e);
            }
        }
    }
    __syncthreads();
    u16* Eo = Eg + (size_t)(t - 1) * 16384;
    for (int idx = tid; idx < 2048; idx += 256)
        ((s8v*)Eo)[idx] = ((const s8v*)Ebuf)[idx];
}

// -------- gold path scores --------------------------------------------------
__global__ __launch_bounds__(256) void score_k(const float* __restrict__ U,
                                               const int* __restrict__ gold,
                                               const void* __restrict__ allowed,
                                               const int* __restrict__ flag,
                                               const u16* __restrict__ HWbf,
                                               const u16* __restrict__ Hbf,
                                               float* __restrict__ accums) {
    const int t = blockIdx.x;
    __shared__ float scr[4];
    float part = 0.f;
    int gp = 0, gc = 0;
    if (t < L_DIM - 1) {
        gp = min(max(gold[t], 0), N_DIM - 1);
        gc = min(max(gold[t + 1], 0), N_DIM - 1);
        const u16* ar = HWbf + (size_t)gp * 512;
        const u16* br = Hbf + (size_t)gc * 512;
        for (int k = threadIdx.x; k < 512; k += 256)
            part += b2f(ar[k]) * b2f(br[k]);
    }
    float tot = blk_sum(part, scr);
    if (threadIdx.x == 0) {
        if (t < L_DIM - 1) {
            int ok = mask_ok(allowed, *flag, (size_t)gc * N_DIM + (size_t)gp);
            atomicAdd(&accums[1], ok ? tot : PEN);
        }
        int g0 = min(max(gold[t], 0), N_DIM - 1);
        atomicAdd(&accums[0], U[(size_t)t * N_DIM + g0]);
    }
}

// ===================== linear-domain MFMA combine tree ======================
// Combine(A,B): S = A_scaled · B (MFMA, K=128), mc[k]=colmax S,
// c' = cB + gA + log mc, G' = S/mc (bf16, re-scaled by exp(c'-g') if out is
// a left child). Dead columns (mc <= MC_MIN) get G'=0, c'=-1e30 sentinel.
__global__ __launch_bounds__(256) void mcomb_k(const u16* __restrict__ Gin,
                                               const float* __restrict__ cin,
                                               const float* __restrict__ gin,
                                               u16* __restrict__ Gout,
                                               float* __restrict__ cout,
                                               float* __restrict__ gout,
                                               int n_in, int last) {
    const int o = blockIdx.x;
    const int tid = threadIdx.x;
    __shared__ __align__(16) u16 As[128 * 136];
    __shared__ __align__(16) u16 BT[128 * 136];
    __shared__ float cb[128], rmc[128], wvv[128], scr[4];
    __shared__ unsigned scm[128];
    const u16* GA = Gin + (size_t)(2 * o) * 16384;
    u16* GO = Gout + (size_t)o * 16384;
    const int roleA = (!last) && ((o & 1) == 0);

    if (2 * o + 1 >= n_in) {   // passthrough (input node is B-role stored)
        if (tid < 128) {
            float cv = cin[(size_t)(2 * o) * 128 + tid];
            cb[tid] = cv;
            cout[(size_t)o * 128 + tid] = cv;
        }
        __syncthreads();
        float xg = (tid < 128) ? cb[tid] : -3.0e38f;
        float gp = blk_max(xg, scr);
        if (tid == 0 && gout) gout[o] = gp;
        if (tid < 128) {
            float d = cb[tid] - gp;
            wvv[tid] = roleA ? ((d > -80.f) ? __expf(d) : 0.f) : 1.0f;
        }
        __syncthreads();
        for (int idx = tid; idx < 2048; idx += 256) {
            s8v vv = ((const s8v*)GA)[idx];
            if (roleA) {
                const int j0 = (idx & 15) * 8;
#pragma unroll
                for (int e = 0; e < 8; ++e)
                    vv[e] = (short)f2bf(b2f((u16)vv[e]) * wvv[j0 + e]);
            }
            ((s8v*)GO)[idx] = vv;
        }
        return;
    }

    const float gA = gin[2 * o];
    const u16* GB = Gin + (size_t)(2 * o + 1) * 16384;
    if (tid < 128) {
        cb[tid] = cin[(size_t)(2 * o + 1) * 128 + tid];
        scm[tid] = 0u;
    }
    __syncthreads();
    // stage: threads 0-127 transpose B row 'tid' into BT; 128-255 copy A rows.
    if (tid < 128) {
        const s8v* src = (const s8v*)(GB + (size_t)tid * 128);
#pragma unroll
        for (int q = 0; q < 16; ++q) {
            s8v v = src[q];
#pragma unroll
            for (int e = 0; e < 8; ++e)
                BT[(q * 8 + e) * 136 + tid] = (u16)v[e];
        }
    } else {
        const int t0 = tid - 128;
#pragma unroll
        for (int q = 0; q < 16; ++q) {
            int gc = q * 128 + t0;
            int r = gc >> 4, qc = gc & 15;
            *(s8v*)&As[r * 136 + qc * 8] = *(const s8v*)(GA + (size_t)r * 128 + qc * 8);
        }
    }
    __syncthreads();

    const int lane = tid & 63, w = tid >> 6;
    const int wr = w >> 1, wc = w & 1;
    const int lq = lane & 15, lh = lane >> 4;
    f32x4 acc[4][4];
#pragma unroll
    for (int a = 0; a < 4; ++a)
#pragma unroll
        for (int b = 0; b < 4; ++b) acc[a][b] = (f32x4){0.f, 0.f, 0.f, 0.f};
#pragma unroll
    for (int kc = 0; kc < 4; ++kc) {
        bfv8 aF[4], bF[4];
        const int off = kc * 32 + lh * 8;
#pragma unroll
        for (int b = 0; b < 4; ++b) {
            aF[b] = *(const bfv8*)&As[(wr * 64 + b * 16 + lq) * 136 + off];
            bF[b] = *(const bfv8*)&BT[(wc * 64 + b * 16 + lq) * 136 + off];
        }
#pragma unroll
        for (int bi = 0; bi < 4; ++bi)
#pragma unroll
            for (int bj = 0; bj < 4; ++bj)
                acc[bi][bj] = __builtin_amdgcn_mfma_f32_16x16x32_bf16(
                    aF[bi], bF[bj], acc[bi][bj], 0, 0, 0);
    }
    // per-column max of S (S >= 0 so float-bit uint compare is monotone)
#pragma unroll
    for (int bj = 0; bj < 4; ++bj) {
        float cm = 0.f;
#pragma unroll
        for (int bi = 0; bi < 4; ++bi)
#pragma unroll
            for (int r = 0; r < 4; ++r) cm = fmaxf(cm, acc[bi][bj][r]);
        cm = fmaxf(cm, __shfl_xor(cm, 16));
        cm = fmaxf(cm, __shfl_xor(cm, 32));
        if (lane < 16) atomicMax(&scm[wc * 64 + bj * 16 + lq], __float_as_uint(cm));
    }
    __syncthreads();
    float cpv = -3.0e38f;
    if (tid < 128) {
        float mc = __uint_as_float(scm[tid]);
        if (mc > MC_MIN) {
            rmc[tid] = 1.0f / mc;                  // <= 1e35, finite
            cpv = cb[tid] + gA + __logf(mc);       // log mc in [-80.6, 4.9]
            if (!(cpv > -1.0e29f)) cpv = -1.0e30f; // catch sentinel cb / NaN
        } else {
            rmc[tid] = 0.f;                        // dead column
            cpv = -1.0e30f;
        }
        cout[(size_t)o * 128 + tid] = cpv;
    }
    float gp = blk_max(cpv, scr);
    if (tid == 0 && gout) gout[o] = gp;
    if (tid < 128) {
        float d = cpv - gp;
        wvv[tid] = roleA ? ((d > -80.f) ? __expf(d) : 0.f) : 1.0f;
    }
    __syncthreads();
    // G' = S * rmc (* wv if left-role) -> As (reuse) -> global, coalesced
#pragma unroll
    for (int bj = 0; bj < 4; ++bj) {
        const int k = wc * 64 + bj * 16 + lq;
        const float sc = rmc[k] * wvv[k];
#pragma unroll
        for (int bi = 0; bi < 4; ++bi)
#pragma unroll
            for (int r = 0; r < 4; ++r) {
                const int i = wr * 64 + bi * 16 + lh * 4 + r;
                float e = acc[bi][bj][r] * sc;
                e = fminf(fmaxf(e, 0.f), 1.0f);     // scrub NaN/overshoot
                As[i * 136 + k] = f2bf(e);
            }
    }
    __syncthreads();
    for (int idx = tid; idx < 2048; idx += 256) {
        int r = idx >> 4, qc = idx & 15;
        *(s8v*)(GO + (size_t)r * 128 + qc * 8) = *(const s8v*)&As[r * 136 + qc * 8];
    }
}

// -------- final: alpha0 through 32 (G,c) nodes, linear dot per step ---------
__global__ __launch_bounds__(256) void tfinal2_k(const u16* __restrict__ G5,
                                                 const float* __restrict__ c5,
                                                 const float* __restrict__ lsmg,
                                                 const float* __restrict__ accums,
                                                 float* __restrict__ out) {
    __shared__ float v[128], ev[128], scr[4];
    __shared__ float psum[2][128];
    __shared__ __align__(16) u16 Gs[16384];
    const int tid = threadIdx.x;
    const int k = tid & 127, h = tid >> 7;
    if (tid < 128) v[tid] = lsmg[tid];   // alpha0
    __syncthreads();
    for (int s = 0; s < 32; ++s) {
        const u16* G = G5 + (size_t)s * 16384;
        for (int idx = tid; idx < 2048; idx += 256)
            ((s8v*)Gs)[idx] = ((const s8v*)G)[idx];
        float x = (tid < 128) ? v[tid] : -3.0e38f;
        float mv = blk_max(x, scr);           // internal syncs fence Gs staging
        if (tid < 128) {
            float d = v[tid] - mv;
            ev[tid] = (d > -80.f) ? __expf(d) : 0.f;
        }
        __syncthreads();
        float dot = 0.f;
        const int i0 = h * 64;
#pragma unroll 8
        for (int i = 0; i < 64; ++i)
            dot += ev[i0 + i] * b2f(Gs[(i0 + i) * 128 + k]);
        psum[h][k] = dot;
        __syncthreads();
        if (tid < 128) {
            float d = psum[0][tid] + psum[1][tid];
            v[tid] = (d > 0.f) ? (c5[s * 128 + tid] + mv + __logf(d)) : -1.0e30f;
        }
        __syncthreads();
    }
    float x = (tid < 128) ? v[tid] : -3.0e38f;
    float mz = blk_max(x, scr);
    float e = (tid < 128) ? __expf(v[tid] - mz) : 0.f;
    float sm = blk_sum(e, scr);
    if (tid == 0) out[0] = mz + __logf(fmaxf(sm, 1e-37f)) - (accums[0] + accums[1]);
}

extern "C" void kernel_launch(void* const* d_in, const int* in_sizes, int n_in,
                              void* d_out, int out_size, void* d_ws, size_t ws_size,
                              hipStream_t stream) {
    const float* U = (const float*)d_in[0];
    const float* H = (const float*)d_in[1];
    const float* W = (const float*)d_in[2];
    const int* gold = (const int*)d_in[3];
    const void* allowed = (const void*)d_in[4];

    char* ws = (char*)d_ws;
    float* accums = (float*)ws;            // [0]=score_unary, [1]=score_pair
    int* flag = (int*)(ws + 8);
    size_t off = 256;
    int* cand = (int*)(ws + off);     off += (size_t)L_DIM * R_DIM * 4;
    float* lsm = (float*)(ws + off);  off += (size_t)L_DIM * R_DIM * 4;
    u16* Hbf = (u16*)(ws + off);      off += (size_t)N_DIM * 512 * 2;      // 16 MB
    u16* HWbf = (u16*)(ws + off);     off += (size_t)N_DIM * 512 * 2;      // 16 MB
    u16* E = (u16*)(ws + off);        off += (size_t)(L_DIM - 1) * 16384 * 2; // 32 MB
    float* cvec = (float*)(ws + off); off += (size_t)(L_DIM - 1) * 128 * 4;
    unsigned* bitsw = (unsigned*)(ws + off); off += (size_t)N_DIM * (N_DIM / 8); // 32 MB
    float* gvec0 = (float*)(ws + off); off += 1024 * 4;
    float* c1 = (float*)(ws + off); off += 512 * 128 * 4;
    float* g1 = (float*)(ws + off); off += 512 * 4;
    float* c2 = (float*)(ws + off); off += 256 * 128 * 4;
    float* g2 = (float*)(ws + off); off += 256 * 4;
    float* c3 = (float*)(ws + off); off += 128 * 128 * 4;
    float* g3 = (float*)(ws + off); off += 128 * 4;
    float* c4 = (float*)(ws + off); off += 64 * 128 * 4;
    float* g4 = (float*)(ws + off); off += 64 * 4;
    float* c5 = (float*)(ws + off); off += 32 * 128 * 4;
    u16* WbfT = (u16*)(ws + off);   off += (size_t)512 * 512 * 2;          // 0.5 MB

    // G-level buffers overlay dead bf16 regions (dead after score_k):
    u16* G1 = Hbf;
    u16* G2 = HWbf;
    u16* G3 = Hbf;
    u16* G4 = HWbf;
    u16* G5 = Hbf;

    hipMemsetAsync(d_ws, 0, 256, stream);
    detect_k<<<1, 256, 0, stream>>>((const unsigned*)d_in[4], flag);
    pack_mask_k<<<(int)(((size_t)N_DIM * N_DIM / 32) / 256), 256, 0, stream>>>(allowed, flag, bitsw);
    topk_lsm_k<<<L_DIM, 256, 0, stream>>>(U, cand, lsm);
    cast_h_k<<<(N_DIM * 512) / (256 * 4), 256, 0, stream>>>(H, Hbf);
    cast_wT_k<<<512, 256, 0, stream>>>(W, WbfT);
    gemm_hw2_k<<<512, 256, 0, stream>>>(Hbf, WbfT, HWbf);
    pair_k<<<L_DIM - 1, 256, 0, stream>>>(cand, lsm, HWbf, Hbf, bitsw, E, cvec, gvec0);
    score_k<<<L_DIM, 256, 0, stream>>>(U, gold, allowed, flag, HWbf, Hbf, accums);
    // MFMA binary tree: 1023 -> 512 -> 256 -> 128 -> 64 -> 32, then 32-step scan
    mcomb_k<<<512, 256, 0, stream>>>(E, cvec, gvec0, G1, c1, g1, 1023, 0);
    mcomb_k<<<256, 256, 0, stream>>>(G1, c1, g1, G2, c2, g2, 512, 0);
    mcomb_k<<<128, 256, 0, stream>>>(G2, c2, g2, G3, c3, g3, 256, 0);
    mcomb_k<<<64, 256, 0, stream>>>(G3, c3, g3, G4, c4, g4, 128, 0);
    mcomb_k<<<32, 256, 0, stream>>>(G4, c4, g4, G5, c5, (float*)0, 64, 1);
    tfinal2_k<<<1, 256, 0, stream>>>(G5, c5, lsm, accums, (float*)d_out);
}

// Round 7
// 1785.091 us; speedup vs baseline: 1.6946x; 1.0343x over previous
//
#include <hip/hip_runtime.h>

typedef unsigned short u16;
typedef __attribute__((ext_vector_type(8))) short s8v;
typedef __attribute__((ext_vector_type(8))) __bf16 bfv8;
typedef __attribute__((ext_vector_type(4))) float f32x4;

#define L_DIM 1024
#define N_DIM 16384
#define R_DIM 128
#define PEN  -10000.0f
#define MC_MIN 1e-35f
#define TCAP 4096

__device__ __forceinline__ float b2f(u16 x) { return __uint_as_float(((unsigned)x) << 16); }
__device__ __forceinline__ u16 f2bf(float f) {
    unsigned u = __float_as_uint(f);
    unsigned r = (u + 0x7FFFu + ((u >> 16) & 1u)) >> 16;
    return (u16)r;
}
__device__ __forceinline__ unsigned fmapu(float f) {
    unsigned u = __float_as_uint(f);
    return (u & 0x80000000u) ? ~u : (u | 0x80000000u);
}
__device__ __forceinline__ float funmap(unsigned u) {
    unsigned b = (u & 0x80000000u) ? (u & 0x7fffffffu) : ~u;
    return __uint_as_float(b);
}
// flag=0: 4-byte elements (int32 OR float32 bools); flag=1: 1-byte elements
__device__ __forceinline__ int mask_ok(const void* al, int fl, size_t idx) {
    if (fl) return ((const unsigned char*)al)[idx] != 0;
    return ((const unsigned*)al)[idx] != 0u;
}

__device__ __forceinline__ float blk_max(float x, float* scr) {
#pragma unroll
    for (int o = 32; o > 0; o >>= 1) x = fmaxf(x, __shfl_xor(x, o));
    __syncthreads();
    if ((threadIdx.x & 63) == 0) scr[threadIdx.x >> 6] = x;
    __syncthreads();
    return fmaxf(fmaxf(scr[0], scr[1]), fmaxf(scr[2], scr[3]));
}
__device__ __forceinline__ float blk_sum(float x, float* scr) {
#pragma unroll
    for (int o = 32; o > 0; o >>= 1) x += __shfl_xor(x, o);
    __syncthreads();
    if ((threadIdx.x & 63) == 0) scr[threadIdx.x >> 6] = x;
    __syncthreads();
    return scr[0] + scr[1] + scr[2] + scr[3];
}

// -------- detect allowed element width --------------------------------------
__global__ void detect_k(const unsigned* __restrict__ a, int* __restrict__ flag) {
    int bad = 0;
    for (int i = threadIdx.x; i < 4096; i += 256) {
        unsigned w = a[i];
        if (w != 0u && w != 1u && w != 0x3F800000u) bad = 1;
    }
    if (bad) *flag = 1;
}

// -------- bit-pack allowed: bits[cur*512 + (prev>>5)] bit (prev&31) ---------
__global__ __launch_bounds__(256) void pack_mask_k(const void* __restrict__ al,
                                                   const int* __restrict__ flag,
                                                   unsigned* __restrict__ bits) {
    const size_t wi = (size_t)blockIdx.x * 256 + threadIdx.x;  // output word idx
    const int fl = *flag;
    unsigned out = 0u;
    if (fl) {
        const uint4* p = (const uint4*)((const unsigned char*)al + wi * 32);
        uint4 a = p[0], b = p[1];
        unsigned v[8] = {a.x, a.y, a.z, a.w, b.x, b.y, b.z, b.w};
#pragma unroll
        for (int q = 0; q < 8; ++q)
#pragma unroll
            for (int e = 0; e < 4; ++e)
                if ((v[q] >> (e * 8)) & 0xFFu) out |= 1u << (q * 4 + e);
    } else {
        const uint4* p = (const uint4*)((const unsigned*)al + wi * 32);
#pragma unroll
        for (int q = 0; q < 8; ++q) {
            uint4 a = p[q];
            if (a.x) out |= 1u << (q * 4 + 0);
            if (a.y) out |= 1u << (q * 4 + 1);
            if (a.z) out |= 1u << (q * 4 + 2);
            if (a.w) out |= 1u << (q * 4 + 3);
        }
    }
    bits[wi] = out;
}

// -------- per-row top-128 (2-global-pass radix select) + log_softmax --------
__global__ __launch_bounds__(256) void topk_lsm_k(const float* __restrict__ U,
                                                  int* __restrict__ candg,
                                                  float* __restrict__ lsmg) {
    const int t = blockIdx.x;
    const float* row = U + (size_t)t * N_DIM;
    __shared__ unsigned hist[4][256];
    __shared__ unsigned keybuf[TCAP];
    __shared__ u16 idxbuf[TCAP];
    __shared__ unsigned dirk[128];
    __shared__ u16 diri[128];
    __shared__ int sel[2];
    __shared__ int nums[2];     // [0]=ndir, [1]=nbuf
    __shared__ int cnts[2];
    __shared__ float vals[128];
    __shared__ int inds[128];
    __shared__ float scr[4];
    const int tid = threadIdx.x;
    const int wv = tid >> 6;

    // pass A: byte histogram (per-wave to avoid hot-bin cross-wave serialization)
    for (int b = tid; b < 1024; b += 256) ((unsigned*)hist)[b] = 0;
    if (tid < 2) { nums[tid] = 0; cnts[tid] = 0; }
    if (tid < 128) { vals[tid] = -1.0e30f; inds[tid] = 0; }
    __syncthreads();
    for (int i = tid; i < N_DIM; i += 256) {
        unsigned u = __float_as_uint(row[i]);
        unsigned k = (u & 0x80000000u) ? ~u : (u | 0x80000000u);
        atomicAdd(&hist[wv][k >> 24], 1u);
    }
    __syncthreads();
    if (tid < 256) hist[0][tid] += hist[1][tid] + hist[2][tid] + hist[3][tid];
    __syncthreads();
    if (tid == 0) {
        int acc = 0, d = 0;
        for (int dig = 255; dig >= 0; --dig) {
            int c = (int)hist[0][dig];
            if (acc + c >= 128) { d = dig; break; }
            acc += c;
        }
        sel[0] = d; sel[1] = acc;
    }
    __syncthreads();
    const unsigned d0 = (unsigned)sel[0];
    int kneed = 128 - sel[1];
    unsigned prefix = d0;
    __syncthreads();

    // pass B: classify (direct winner / candidate)
    for (int i = tid; i < N_DIM; i += 256) {
        unsigned u = __float_as_uint(row[i]);
        unsigned k = (u & 0x80000000u) ? ~u : (u | 0x80000000u);
        unsigned by = k >> 24;
        if (by > d0) {
            int p = atomicAdd(&nums[0], 1);
            if (p < 128) { dirk[p] = k; diri[p] = (u16)i; }
        } else if (by == d0) {
            int p = atomicAdd(&nums[1], 1);
            if (p < TCAP) { keybuf[p] = k; idxbuf[p] = (u16)i; }
        }
    }
    __syncthreads();
    const int ndir = min(nums[0], 128);
    const int nbuf = nums[1];

    if (nbuf <= TCAP) {
        // radix passes 1-3 over the LDS candidate buffer
        for (int pass = 1; pass < 4; ++pass) {
            const int sh = 24 - pass * 8;
            if (tid < 256) hist[0][tid] = 0;
            __syncthreads();
            for (int j = tid; j < nbuf; j += 256) {
                unsigned k = keybuf[j];
                if ((k >> (sh + 8)) == prefix) atomicAdd(&hist[0][(k >> sh) & 255u], 1u);
            }
            __syncthreads();
            if (tid == 0) {
                int acc = 0, d = 0;
                for (int dig = 255; dig >= 0; --dig) {
                    int c = (int)hist[0][dig];
                    if (acc + c >= kneed) { d = dig; break; }
                    acc += c;
                }
                sel[0] = d; sel[1] = acc;
            }
            __syncthreads();
            kneed -= sel[1];
            prefix = (prefix << 8) | (unsigned)sel[0];
            __syncthreads();
        }
        const unsigned K = prefix;
        for (int j = tid; j < ndir; j += 256) {
            int p = atomicAdd(&cnts[0], 1);
            if (p < 128) { vals[p] = funmap(dirk[j]); inds[p] = diri[j]; }
        }
        for (int j = tid; j < nbuf; j += 256) {
            unsigned k = keybuf[j];
            if (k > K) {
                int p = atomicAdd(&cnts[0], 1);
                if (p < 128) { vals[p] = funmap(k); inds[p] = idxbuf[j]; }
            }
        }
        __syncthreads();
        const int cgt = min(cnts[0], 128);
        for (int j = tid; j < nbuf; j += 256) {
            unsigned k = keybuf[j];
            if (k == K) {
                int p = atomicAdd(&cnts[1], 1);
                if (cgt + p < 128) { vals[cgt + p] = funmap(k); inds[cgt + p] = idxbuf[j]; }
            }
        }
        __syncthreads();
    } else {
        // fallback (adversarial key distributions): original global-row passes
        for (int pass = 1; pass < 4; ++pass) {
            const int sh = 24 - pass * 8;
            if (tid < 256) hist[0][tid] = 0;
            __syncthreads();
            for (int i = tid; i < N_DIM; i += 256) {
                unsigned u = __float_as_uint(row[i]);
                unsigned k = (u & 0x80000000u) ? ~u : (u | 0x80000000u);
                if ((k >> (sh + 8)) == prefix) atomicAdd(&hist[0][(k >> sh) & 255u], 1u);
            }
            __syncthreads();
            if (tid == 0) {
                int acc = 0, d = 0;
                for (int dig = 255; dig >= 0; --dig) {
                    int c = (int)hist[0][dig];
                    if (acc + c >= kneed) { d = dig; break; }
                    acc += c;
                }
                sel[0] = d; sel[1] = acc;
            }
            __syncthreads();
            kneed -= sel[1];
            prefix = (prefix << 8) | (unsigned)sel[0];
            __syncthreads();
        }
        const unsigned K = prefix;
        for (int i = tid; i < N_DIM; i += 256) {
            float f = row[i];
            unsigned k = fmapu(f);
            if (k > K) {
                int p = atomicAdd(&cnts[0], 1);
                if (p < 128) { vals[p] = f; inds[p] = i; }
            }
        }
        __syncthreads();
        const int cgt = min(cnts[0], 128);
        for (int i = tid; i < N_DIM; i += 256) {
            float f = row[i];
            unsigned k = fmapu(f);
            if (k == K) {
                int p = atomicAdd(&cnts[1], 1);
                if (cgt + p < 128) { vals[cgt + p] = f; inds[cgt + p] = i; }
            }
        }
        __syncthreads();
    }

    float xv = (tid < 128) ? vals[tid] : -3.0e38f;
    float mx = blk_max(xv, scr);
    float ex = (tid < 128) ? __expf(vals[tid] - mx) : 0.f;
    float sm = blk_sum(ex, scr);
    float lse = mx + __logf(fmaxf(sm, 1e-37f));
    if (tid < 128) {
        candg[t * 128 + tid] = min(max(inds[tid], 0), N_DIM - 1);
        lsmg[t * 128 + tid] = vals[tid] - lse;
    }
}

// -------- cast H to bf16 ----------------------------------------------------
__global__ void cast_h_k(const float* __restrict__ H, u16* __restrict__ Hbf) {
    size_t base = ((size_t)blockIdx.x * 256 + threadIdx.x) * 4;
    float4 f = *(const float4*)(H + base);
    ushort4 o;
    o.x = f2bf(f.x); o.y = f2bf(f.y); o.z = f2bf(f.z); o.w = f2bf(f.w);
    *(ushort4*)(Hbf + base) = o;
}

// -------- cast W^T to bf16 (for MFMA B-operand rows) ------------------------
__global__ __launch_bounds__(256) void cast_wT_k(const float* __restrict__ W,
                                                 u16* __restrict__ WT) {
    const int c = blockIdx.x;
    for (int k = threadIdx.x; k < 512; k += 256)
        WT[(size_t)c * 512 + k] = f2bf(W[(size_t)k * 512 + c]);
}

// -------- HW = Hbf @ Wbf via MFMA -------------------------------------------
__global__ __launch_bounds__(256) void gemm_hw2_k(const u16* __restrict__ Hbf,
                                                  const u16* __restrict__ WT,
                                                  u16* __restrict__ HWbf) {
    const int bm = blockIdx.x >> 2, bn = blockIdx.x & 3;
    const int r0 = bm * 128, c0 = bn * 128;
    __shared__ __align__(16) u16 tile[2][128 * 64];
    const int tid = threadIdx.x;
    const int lane = tid & 63, w = tid >> 6;
    const int wr = w >> 1, wc = w & 1;
    const int srow = lane >> 3, slot = lane & 7;
    const int lq = lane & 15, lh = lane >> 4;

    const u16* pA[4]; const u16* pB[4]; int wadr[4];
#pragma unroll
    for (int q = 0; q < 4; ++q) {
        int r = (w * 4 + q) * 8 + srow;
        pA[q] = Hbf + (size_t)(r0 + r) * 512 + slot * 8;
        pB[q] = WT  + (size_t)(c0 + r) * 512 + slot * 8;
        wadr[q] = r * 64 + ((slot ^ srow) * 8);
    }
    s8v rA[4], rB[4];
#pragma unroll
    for (int q = 0; q < 4; ++q) { rA[q] = *(const s8v*)pA[q]; rB[q] = *(const s8v*)pB[q]; }

    f32x4 acc[4][4];
#pragma unroll
    for (int a = 0; a < 4; ++a)
#pragma unroll
        for (int b = 0; b < 4; ++b) acc[a][b] = (f32x4){0.f, 0.f, 0.f, 0.f};

    for (int s = 0; s < 8; ++s) {
        __syncthreads();
#pragma unroll
        for (int q = 0; q < 4; ++q) {
            *(s8v*)&tile[0][wadr[q]] = rA[q];
            *(s8v*)&tile[1][wadr[q]] = rB[q];
        }
        __syncthreads();
        if (s < 7) {
#pragma unroll
            for (int q = 0; q < 4; ++q) {
                pA[q] += 64; pB[q] += 64;
                rA[q] = *(const s8v*)pA[q];
                rB[q] = *(const s8v*)pB[q];
            }
        }
#pragma unroll
        for (int kk = 0; kk < 2; ++kk) {
            bfv8 aF[4], bF[4];
            const int sl = (((kk << 2) | lh) ^ (lq & 7)) * 8;
#pragma unroll
            for (int b = 0; b < 4; ++b) {
                aF[b] = *(const bfv8*)&tile[0][(wr * 64 + b * 16 + lq) * 64 + sl];
                bF[b] = *(const bfv8*)&tile[1][(wc * 64 + b * 16 + lq) * 64 + sl];
            }
#pragma unroll
            for (int bi = 0; bi < 4; ++bi)
#pragma unroll
                for (int bj = 0; bj < 4; ++bj)
                    acc[bi][bj] = __builtin_amdgcn_mfma_f32_16x16x32_bf16(
                        aF[bi], bF[bj], acc[bi][bj], 0, 0, 0);
        }
    }
#pragma unroll
    for (int bj = 0; bj < 4; ++bj) {
        const int j = wc * 64 + bj * 16 + lq;
#pragma unroll
        for (int bi = 0; bi < 4; ++bi)
#pragma unroll
            for (int r = 0; r < 4; ++r) {
                const int i = wr * 64 + bi * 16 + lh * 4 + r;
                HWbf[(size_t)(r0 + i) * 512 + c0 + j] = f2bf(acc[bi][bj][r]);
            }
    }
}

// -------- per-step pair matrix via MFMA -> (E row-major bf16, c fp32) -------
// Node rep: P[i][j] = log E[i][j] + cvec[j], E column-normalized (max 1).
// Left-role nodes (even m, m != 1022) are stored pre-scaled:
// E' = E * diag(exp(cvec - g)), with scalar g = max(cvec) in gvec0[m].
__global__ __launch_bounds__(256) void pair_k(const int* __restrict__ candg,
                                              const float* __restrict__ lsmg,
                                              const u16* __restrict__ HWbf,
                                              const u16* __restrict__ Hbf,
                                              const unsigned* __restrict__ bits,
                                              u16* __restrict__ Eg,
                                              float* __restrict__ cvec,
                                              float* __restrict__ gvec0) {
    const int t = blockIdx.x + 1;
    __shared__ __align__(16) u16 tile[2][128 * 64];
    __shared__ int sprev[128], scur[128];
    __shared__ unsigned maskw[128][4];  // maskw[j][i>>5] bit (i&31)
    __shared__ unsigned scm_u[128];
    __shared__ float cmf[128], cvf[128], wvv[128], scr[4];
    const int tid = threadIdx.x;
    if (tid < 128) {
        sprev[tid] = min(max(candg[(t - 1) * 128 + tid], 0), N_DIM - 1);
        scur[tid]  = min(max(candg[t * 128 + tid], 0), N_DIM - 1);
        scm_u[tid] = 0u;
    }
    __syncthreads();

    const int lane = tid & 63, w = tid >> 6;
    const int wr = w >> 1, wc = w & 1;      // wave tile: rows wr*64.., cols wc*64..
    const int srow = lane >> 3, slot = lane & 7;
    const int lq = lane & 15, lh = lane >> 4;

    const u16* pA[4]; const u16* pB[4]; int wadr[4];
#pragma unroll
    for (int q = 0; q < 4; ++q) {
        int r = (w * 4 + q) * 8 + srow;
        pA[q] = HWbf + (size_t)sprev[r] * 512 + slot * 8;
        pB[q] = Hbf  + (size_t)scur[r] * 512 + slot * 8;
        wadr[q] = r * 64 + ((slot ^ srow) * 8);
    }
    s8v rA[4], rB[4];
#pragma unroll
    for (int q = 0; q < 4; ++q) { rA[q] = *(const s8v*)pA[q]; rB[q] = *(const s8v*)pB[q]; }

    // mask gather from bit-packed allowed (L3-resident); overlaps staging latency
    {
        const int j = tid & 127, ihalf = tid >> 7;
        const unsigned* rowp = bits + (size_t)scur[j] * 512;
        unsigned mw0 = 0u, mw1 = 0u;
#pragma unroll 8
        for (int kb = 0; kb < 32; ++kb) {
            int p0 = sprev[ihalf * 64 + kb];
            int p1 = sprev[ihalf * 64 + 32 + kb];
            mw0 |= ((rowp[p0 >> 5] >> (p0 & 31)) & 1u) << kb;
            mw1 |= ((rowp[p1 >> 5] >> (p1 & 31)) & 1u) << kb;
        }
        maskw[j][ihalf * 2]     = mw0;
        maskw[j][ihalf * 2 + 1] = mw1;
    }

    f32x4 acc[4][4];
#pragma unroll
    for (int a = 0; a < 4; ++a)
#pragma unroll
        for (int b = 0; b < 4; ++b) acc[a][b] = (f32x4){0.f, 0.f, 0.f, 0.f};

    for (int s = 0; s < 8; ++s) {
        __syncthreads();
#pragma unroll
        for (int q = 0; q < 4; ++q) {
            *(s8v*)&tile[0][wadr[q]] = rA[q];
            *(s8v*)&tile[1][wadr[q]] = rB[q];
        }
        __syncthreads();
        if (s < 7) {
#pragma unroll
            for (int q = 0; q < 4; ++q) {
                pA[q] += 64; pB[q] += 64;
                rA[q] = *(const s8v*)pA[q];
                rB[q] = *(const s8v*)pB[q];
            }
        }
#pragma unroll
        for (int kk = 0; kk < 2; ++kk) {
            bfv8 aF[4], bF[4];
            const int sl = (((kk << 2) | lh) ^ (lq & 7)) * 8;
#pragma unroll
            for (int b = 0; b < 4; ++b) {
                aF[b] = *(const bfv8*)&tile[0][(wr * 64 + b * 16 + lq) * 64 + sl];
                bF[b] = *(const bfv8*)&tile[1][(wc * 64 + b * 16 + lq) * 64 + sl];
            }
#pragma unroll
            for (int bi = 0; bi < 4; ++bi)
#pragma unroll
                for (int bj = 0; bj < 4; ++bj)
                    acc[bi][bj] = __builtin_amdgcn_mfma_f32_16x16x32_bf16(
                        aF[bi], bF[bj], acc[bi][bj], 0, 0, 0);
        }
    }

    // epilogue: mask, per-column (j) max over i, exp-normalize
#pragma unroll
    for (int bj = 0; bj < 4; ++bj) {
        const int j = wc * 64 + bj * 16 + lq;
        float cm = -3.0e38f;
#pragma unroll
        for (int bi = 0; bi < 4; ++bi) {
#pragma unroll
            for (int r = 0; r < 4; ++r) {
                int i = wr * 64 + bi * 16 + lh * 4 + r;
                float v = acc[bi][bj][r];
                if (!((maskw[j][i >> 5] >> (i & 31)) & 1u)) v += PEN;
                acc[bi][bj][r] = v;
                cm = fmaxf(cm, v);
            }
        }
        cm = fmaxf(cm, __shfl_xor(cm, 16));
        cm = fmaxf(cm, __shfl_xor(cm, 32));
        if (lane < 16) atomicMax(&scm_u[j], fmapu(cm));
    }
    __syncthreads();
    if (tid < 128) {
        float cm = funmap(scm_u[tid]);
        cmf[tid] = cm;
        float cv = cm + lsmg[(size_t)t * 128 + tid];
        cvf[tid] = cv;
        cvec[(size_t)(t - 1) * 128 + tid] = cv;
    }
    __syncthreads();
    const int m = t - 1;
    const int roleA = ((m & 1) == 0) && (m != 1022);
    float xg = (tid < 128) ? cvf[tid] : -3.0e38f;
    float g = blk_max(xg, scr);
    if (tid == 0) gvec0[m] = g;
    if (tid < 128) wvv[tid] = roleA ? __expf(cvf[tid] - g) : 1.0f;
    __syncthreads();
    // restage E through (now dead) tiles for coalesced stores
    u16* Ebuf = &tile[0][0];                // 16384 u16, contiguous
#pragma unroll
    for (int bj = 0; bj < 4; ++bj) {
        const int j = wc * 64 + bj * 16 + lq;
        const float cm = cmf[j];
        const float wj = wvv[j];
#pragma unroll
        for (int bi = 0; bi < 4; ++bi) {
#pragma unroll
            for (int r = 0; r < 4; ++r) {
                int i = wr * 64 + bi * 16 + lh * 4 + r;
                float e = __expf(acc[bi][bj][r] - cm);   // arg <= 0 by construction
                e = fminf(fmaxf(e, 0.f), 1.0f) * wj;     // scrub, apply role scale
                Ebuf[i * 128 + j] = f2bf(e);
            }
        }
    }
    __syncthreads();
    u16* Eo = Eg + (size_t)(t - 1) * 16384;
    for (int idx = tid; idx < 2048; idx += 256)
        ((s8v*)Eo)[idx] = ((const s8v*)Ebuf)[idx];
}

// -------- gold path scores --------------------------------------------------
__global__ __launch_bounds__(256) void score_k(const float* __restrict__ U,
                                               const int* __restrict__ gold,
                                               const void* __restrict__ allowed,
                                               const int* __restrict__ flag,
                                               const u16* __restrict__ HWbf,
                                               const u16* __restrict__ Hbf,
                                               float* __restrict__ accums) {
    const int t = blockIdx.x;
    __shared__ float scr[4];
    float part = 0.f;
    int gp = 0, gc = 0;
    if (t < L_DIM - 1) {
        gp = min(max(gold[t], 0), N_DIM - 1);
        gc = min(max(gold[t + 1], 0), N_DIM - 1);
        const u16* ar = HWbf + (size_t)gp * 512;
        const u16* br = Hbf + (size_t)gc * 512;
        for (int k = threadIdx.x; k < 512; k += 256)
            part += b2f(ar[k]) * b2f(br[k]);
    }
    float tot = blk_sum(part, scr);
    if (threadIdx.x == 0) {
        if (t < L_DIM - 1) {
            int ok = mask_ok(allowed, *flag, (size_t)gc * N_DIM + (size_t)gp);
            atomicAdd(&accums[1], ok ? tot : PEN);
        }
        int g0 = min(max(gold[t], 0), N_DIM - 1);
        atomicAdd(&accums[0], U[(size_t)t * N_DIM + g0]);
    }
}

// ===================== linear-domain MFMA combine tree ======================
// Combine(A,B): S = A_scaled · B (MFMA, K=128), mc[k]=colmax S,
// c' = cB + gA + log mc, G' = S/mc (bf16, re-scaled by exp(c'-g') if out is
// a left child). Dead columns (mc <= MC_MIN) get G'=0, c'=-1e30 sentinel.
__global__ __launch_bounds__(256) void mcomb_k(const u16* __restrict__ Gin,
                                               const float* __restrict__ cin,
                                               const float* __restrict__ gin,
                                               u16* __restrict__ Gout,
                                               float* __restrict__ cout,
                                               float* __restrict__ gout,
                                               int n_in, int last) {
    const int o = blockIdx.x;
    const int tid = threadIdx.x;
    __shared__ __align__(16) u16 As[128 * 136];
    __shared__ __align__(16) u16 BT[128 * 136];
    __shared__ float cb[128], rmc[128], wvv[128], scr[4];
    __shared__ unsigned scm[128];
    const u16* GA = Gin + (size_t)(2 * o) * 16384;
    u16* GO = Gout + (size_t)o * 16384;
    const int roleA = (!last) && ((o & 1) == 0);

    if (2 * o + 1 >= n_in) {   // passthrough (input node is B-role stored)
        if (tid < 128) {
            float cv = cin[(size_t)(2 * o) * 128 + tid];
            cb[tid] = cv;
            cout[(size_t)o * 128 + tid] = cv;
        }
        __syncthreads();
        float xg = (tid < 128) ? cb[tid] : -3.0e38f;
        float gp = blk_max(xg, scr);
        if (tid == 0 && gout) gout[o] = gp;
        if (tid < 128) {
            float d = cb[tid] - gp;
            wvv[tid] = roleA ? ((d > -80.f) ? __expf(d) : 0.f) : 1.0f;
        }
        __syncthreads();
        for (int idx = tid; idx < 2048; idx += 256) {
            s8v vv = ((const s8v*)GA)[idx];
            if (roleA) {
                const int j0 = (idx & 15) * 8;
#pragma unroll
                for (int e = 0; e < 8; ++e)
                    vv[e] = (short)f2bf(b2f((u16)vv[e]) * wvv[j0 + e]);
            }
            ((s8v*)GO)[idx] = vv;
        }
        return;
    }

    const float gA = gin[2 * o];
    const u16* GB = Gin + (size_t)(2 * o + 1) * 16384;
    if (tid < 128) {
        cb[tid] = cin[(size_t)(2 * o + 1) * 128 + tid];
        scm[tid] = 0u;
    }
    __syncthreads();
    // stage: threads 0-127 transpose B row 'tid' into BT; 128-255 copy A rows.
    if (tid < 128) {
        const s8v* src = (const s8v*)(GB + (size_t)tid * 128);
#pragma unroll
        for (int q = 0; q < 16; ++q) {
            s8v v = src[q];
#pragma unroll
            for (int e = 0; e < 8; ++e)
                BT[(q * 8 + e) * 136 + tid] = (u16)v[e];
        }
    } else {
        const int t0 = tid - 128;
#pragma unroll
        for (int q = 0; q < 16; ++q) {
            int gc = q * 128 + t0;
            int r = gc >> 4, qc = gc & 15;
            *(s8v*)&As[r * 136 + qc * 8] = *(const s8v*)(GA + (size_t)r * 128 + qc * 8);
        }
    }
    __syncthreads();

    const int lane = tid & 63, w = tid >> 6;
    const int wr = w >> 1, wc = w & 1;
    const int lq = lane & 15, lh = lane >> 4;
    f32x4 acc[4][4];
#pragma unroll
    for (int a = 0; a < 4; ++a)
#pragma unroll
        for (int b = 0; b < 4; ++b) acc[a][b] = (f32x4){0.f, 0.f, 0.f, 0.f};
#pragma unroll
    for (int kc = 0; kc < 4; ++kc) {
        bfv8 aF[4], bF[4];
        const int off = kc * 32 + lh * 8;
#pragma unroll
        for (int b = 0; b < 4; ++b) {
            aF[b] = *(const bfv8*)&As[(wr * 64 + b * 16 + lq) * 136 + off];
            bF[b] = *(const bfv8*)&BT[(wc * 64 + b * 16 + lq) * 136 + off];
        }
#pragma unroll
        for (int bi = 0; bi < 4; ++bi)
#pragma unroll
            for (int bj = 0; bj < 4; ++bj)
                acc[bi][bj] = __builtin_amdgcn_mfma_f32_16x16x32_bf16(
                    aF[bi], bF[bj], acc[bi][bj], 0, 0, 0);
    }
    // per-column max of S (S >= 0 so float-bit uint compare is monotone)
#pragma unroll
    for (int bj = 0; bj < 4; ++bj) {
        float cm = 0.f;
#pragma unroll
        for (int bi = 0; bi < 4; ++bi)
#pragma unroll
            for (int r = 0; r < 4; ++r) cm = fmaxf(cm, acc[bi][bj][r]);
        cm = fmaxf(cm, __shfl_xor(cm, 16));
        cm = fmaxf(cm, __shfl_xor(cm, 32));
        if (lane < 16) atomicMax(&scm[wc * 64 + bj * 16 + lq], __float_as_uint(cm));
    }
    __syncthreads();
    float cpv = -3.0e38f;
    if (tid < 128) {
        float mc = __uint_as_float(scm[tid]);
        if (mc > MC_MIN) {
            rmc[tid] = 1.0f / mc;                  // <= 1e35, finite
            cpv = cb[tid] + gA + __logf(mc);       // log mc in [-80.6, 4.9]
            if (!(cpv > -1.0e29f)) cpv = -1.0e30f; // catch sentinel cb / NaN
        } else {
            rmc[tid] = 0.f;                        // dead column
            cpv = -1.0e30f;
        }
        cout[(size_t)o * 128 + tid] = cpv;
    }
    float gp = blk_max(cpv, scr);
    if (tid == 0 && gout) gout[o] = gp;
    if (tid < 128) {
        float d = cpv - gp;
        wvv[tid] = roleA ? ((d > -80.f) ? __expf(d) : 0.f) : 1.0f;
    }
    __syncthreads();
    // G' = S * rmc (* wv if left-role) -> As (reuse) -> global, coalesced
#pragma unroll
    for (int bj = 0; bj < 4; ++bj) {
        const int k = wc * 64 + bj * 16 + lq;
        const float sc = rmc[k] * wvv[k];
#pragma unroll
        for (int bi = 0; bi < 4; ++bi)
#pragma unroll
            for (int r = 0; r < 4; ++r) {
                const int i = wr * 64 + bi * 16 + lh * 4 + r;
                float e = acc[bi][bj][r] * sc;
                e = fminf(fmaxf(e, 0.f), 1.0f);     // scrub NaN/overshoot
                As[i * 136 + k] = f2bf(e);
            }
    }
    __syncthreads();
    for (int idx = tid; idx < 2048; idx += 256) {
        int r = idx >> 4, qc = idx & 15;
        *(s8v*)(GO + (size_t)r * 128 + qc * 8) = *(const s8v*)&As[r * 136 + qc * 8];
    }
}

// -------- final: logZ from the single root node (G,c) + alpha0 --------------
// Root M[i][k] = log G[i][k] + c[k]; logZ = LSE_{i,k}(alpha0[i] + M[i][k]).
__global__ __launch_bounds__(256) void tfinal3_k(const u16* __restrict__ Gr,
                                                 const float* __restrict__ cr,
                                                 const float* __restrict__ lsmg,
                                                 const float* __restrict__ accums,
                                                 float* __restrict__ out) {
    __shared__ float ev[128], scr[4];
    __shared__ float psum[2][128];
    __shared__ float v[128];
    __shared__ __align__(16) u16 Gs[16384];
    const int tid = threadIdx.x;
    const int k = tid & 127, h = tid >> 7;
    for (int idx = tid; idx < 2048; idx += 256)
        ((s8v*)Gs)[idx] = ((const s8v*)Gr)[idx];
    float x = (tid < 128) ? lsmg[tid] : -3.0e38f;
    float mv = blk_max(x, scr);               // internal syncs fence Gs staging
    if (tid < 128) {
        float d = lsmg[tid] - mv;
        ev[tid] = (d > -80.f) ? __expf(d) : 0.f;
    }
    __syncthreads();
    float dot = 0.f;
    const int i0 = h * 64;
#pragma unroll 8
    for (int i = 0; i < 64; ++i)
        dot += ev[i0 + i] * b2f(Gs[(i0 + i) * 128 + k]);
    psum[h][k] = dot;
    __syncthreads();
    if (tid < 128) {
        float d = psum[0][tid] + psum[1][tid];
        v[tid] = (d > 0.f) ? (cr[tid] + mv + __logf(d)) : -1.0e30f;
    }
    __syncthreads();
    float y = (tid < 128) ? v[tid] : -3.0e38f;
    float mz = blk_max(y, scr);
    float e = (tid < 128) ? __expf(v[tid] - mz) : 0.f;
    float sm = blk_sum(e, scr);
    if (tid == 0) out[0] = mz + __logf(fmaxf(sm, 1e-37f)) - (accums[0] + accums[1]);
}

extern "C" void kernel_launch(void* const* d_in, const int* in_sizes, int n_in,
                              void* d_out, int out_size, void* d_ws, size_t ws_size,
                              hipStream_t stream) {
    const float* U = (const float*)d_in[0];
    const float* H = (const float*)d_in[1];
    const float* W = (const float*)d_in[2];
    const int* gold = (const int*)d_in[3];
    const void* allowed = (const void*)d_in[4];

    char* ws = (char*)d_ws;
    float* accums = (float*)ws;            // [0]=score_unary, [1]=score_pair
    int* flag = (int*)(ws + 8);
    size_t off = 256;
    int* cand = (int*)(ws + off);     off += (size_t)L_DIM * R_DIM * 4;
    float* lsm = (float*)(ws + off);  off += (size_t)L_DIM * R_DIM * 4;
    u16* Hbf = (u16*)(ws + off);      off += (size_t)N_DIM * 512 * 2;      // 16 MB
    u16* HWbf = (u16*)(ws + off);     off += (size_t)N_DIM * 512 * 2;      // 16 MB
    u16* E = (u16*)(ws + off);        off += (size_t)(L_DIM - 1) * 16384 * 2; // 32 MB
    float* cvec = (float*)(ws + off); off += (size_t)(L_DIM - 1) * 128 * 4;
    unsigned* bitsw = (unsigned*)(ws + off); off += (size_t)N_DIM * (N_DIM / 8); // 32 MB
    float* gvec0 = (float*)(ws + off); off += 1024 * 4;
    float* c1 = (float*)(ws + off); off += 512 * 128 * 4;
    float* g1 = (float*)(ws + off); off += 512 * 4;
    float* c2 = (float*)(ws + off); off += 256 * 128 * 4;
    float* g2 = (float*)(ws + off); off += 256 * 4;
    float* c3 = (float*)(ws + off); off += 128 * 128 * 4;
    float* g3 = (float*)(ws + off); off += 128 * 4;
    float* c4 = (float*)(ws + off); off += 64 * 128 * 4;
    float* g4 = (float*)(ws + off); off += 64 * 4;
    float* c5 = (float*)(ws + off); off += 32 * 128 * 4;
    float* g5 = (float*)(ws + off); off += 32 * 4;
    float* c6 = (float*)(ws + off); off += 16 * 128 * 4;
    float* g6 = (float*)(ws + off); off += 16 * 4;
    float* c7 = (float*)(ws + off); off += 8 * 128 * 4;
    float* g7 = (float*)(ws + off); off += 8 * 4;
    float* c8 = (float*)(ws + off); off += 4 * 128 * 4;
    float* g8 = (float*)(ws + off); off += 4 * 4;
    float* c9 = (float*)(ws + off); off += 2 * 128 * 4;
    float* g9 = (float*)(ws + off); off += 2 * 4;
    float* c10 = (float*)(ws + off); off += 128 * 4;
    u16* WbfT = (u16*)(ws + off);   off += (size_t)512 * 512 * 2;          // 0.5 MB

    // G-level buffers ping-pong dead bf16 regions (dead after score_k):
    u16* G1 = Hbf;
    u16* G2 = HWbf;
    u16* G3 = Hbf;
    u16* G4 = HWbf;
    u16* G5 = Hbf;
    u16* G6 = HWbf;
    u16* G7 = Hbf;
    u16* G8 = HWbf;
    u16* G9 = Hbf;
    u16* G10 = HWbf;

    hipMemsetAsync(d_ws, 0, 256, stream);
    detect_k<<<1, 256, 0, stream>>>((const unsigned*)d_in[4], flag);
    pack_mask_k<<<(int)(((size_t)N_DIM * N_DIM / 32) / 256), 256, 0, stream>>>(allowed, flag, bitsw);
    topk_lsm_k<<<L_DIM, 256, 0, stream>>>(U, cand, lsm);
    cast_h_k<<<(N_DIM * 512) / (256 * 4), 256, 0, stream>>>(H, Hbf);
    cast_wT_k<<<512, 256, 0, stream>>>(W, WbfT);
    gemm_hw2_k<<<512, 256, 0, stream>>>(Hbf, WbfT, HWbf);
    pair_k<<<L_DIM - 1, 256, 0, stream>>>(cand, lsm, HWbf, Hbf, bitsw, E, cvec, gvec0);
    score_k<<<L_DIM, 256, 0, stream>>>(U, gold, allowed, flag, HWbf, Hbf, accums);
    // MFMA binary tree all the way to the root: 1023 -> ... -> 1
    mcomb_k<<<512, 256, 0, stream>>>(E, cvec, gvec0, G1, c1, g1, 1023, 0);
    mcomb_k<<<256, 256, 0, stream>>>(G1, c1, g1, G2, c2, g2, 512, 0);
    mcomb_k<<<128, 256, 0, stream>>>(G2, c2, g2, G3, c3, g3, 256, 0);
    mcomb_k<<<64, 256, 0, stream>>>(G3, c3, g3, G4, c4, g4, 128, 0);
    mcomb_k<<<32, 256, 0, stream>>>(G4, c4, g4, G5, c5, g5, 64, 0);
    mcomb_k<<<16, 256, 0, stream>>>(G5, c5, g5, G6, c6, g6, 32, 0);
    mcomb_k<<<8, 256, 0, stream>>>(G6, c6, g6, G7, c7, g7, 16, 0);
    mcomb_k<<<4, 256, 0, stream>>>(G7, c7, g7, G8, c8, g8, 8, 0);
    mcomb_k<<<2, 256, 0, stream>>>(G8, c8, g8, G9, c9, g9, 4, 0);
    mcomb_k<<<1, 256, 0, stream>>>(G9, c9, g9, G10, c10, (float*)0, 2, 1);
    tfinal3_k<<<1, 256, 0, stream>>>(G10, c10, lsm, accums, (float*)d_out);
}